// Round 7
// baseline (770.396 us; speedup 1.0000x reference)
//
#include <hip/hip_runtime.h>

#define NN 100000
#define EE 3200000
#define HH 128
#define CC 40
#define KK 5
#define NBUK 391   // ceil(NN/256) buckets of 256 nodes
#define CH 8192    // edges per coarse-scatter block

typedef __attribute__((ext_vector_type(8))) short bf16x8;
typedef __attribute__((ext_vector_type(4))) float f32x4;

__device__ inline float b2f(unsigned short u) {
    union { unsigned int i; float f; } c;
    c.i = ((unsigned int)u) << 16;
    return c.f;
}
__device__ inline float b2f_lo(unsigned int u) {
    union { unsigned int i; float f; } c;
    c.i = u << 16;
    return c.f;
}
__device__ inline float b2f_hi(unsigned int u) {
    union { unsigned int i; float f; } c;
    c.i = u & 0xFFFF0000u;
    return c.f;
}
__device__ inline unsigned short f2b(float f) {
    union { float f; unsigned int i; } c;
    c.f = f;
    unsigned int r = c.i + 0x7FFFu + ((c.i >> 16) & 1u);
    return (unsigned short)(r >> 16);
}

// ---------------------------------------------------------------- CSR build

__global__ __launch_bounds__(256) void hist_kernel(const int* __restrict__ dst,
                                                   int* __restrict__ deg) {
    int e = blockIdx.x * 256 + threadIdx.x;
    if (e < EE) atomicAdd(&deg[dst[e]], 1);
}

__global__ __launch_bounds__(256) void scan1_kernel(const int* __restrict__ deg,
                                                    int* __restrict__ partial) {
    __shared__ int sh[256];
    int t = threadIdx.x;
    int base = blockIdx.x * 1024 + t * 4;
    int s = 0;
#pragma unroll
    for (int j = 0; j < 4; ++j) {
        int idx = base + j;
        if (idx < NN) s += deg[idx];
    }
    sh[t] = s;
    __syncthreads();
    for (int off = 128; off > 0; off >>= 1) {
        if (t < off) sh[t] += sh[t + off];
        __syncthreads();
    }
    if (t == 0) partial[blockIdx.x] = sh[0];
}

__global__ void scan2_kernel(int* __restrict__ partial, int nb, int* __restrict__ offsets,
                             const float* __restrict__ hc0, const float* __restrict__ hc1,
                             float* __restrict__ wsm) {
    __shared__ int sh[128];
    int t = threadIdx.x;
    int v = (t < nb) ? partial[t] : 0;
    sh[t] = v;
    __syncthreads();
    for (int off = 1; off < 128; off <<= 1) {
        int x = (t >= off) ? sh[t - off] : 0;
        __syncthreads();
        sh[t] += x;
        __syncthreads();
    }
    if (t < nb) partial[t] = sh[t] - v;  // exclusive block offsets
    if (t == 0) {
        offsets[NN] = EE;
        for (int which = 0; which < 2; ++which) {
            const float* hc = which ? hc1 : hc0;
            float mx = hc[0];
            for (int k = 1; k < KK; ++k) mx = fmaxf(mx, hc[k]);
            float ex0 = expf(hc[0] - mx), ex1 = expf(hc[1] - mx), ex2 = expf(hc[2] - mx);
            float ex3 = expf(hc[3] - mx), ex4 = expf(hc[4] - mx);
            float sum = ex0 + ex1 + ex2 + ex3 + ex4;
            float inv = 1.0f / sum;
            wsm[which * 8 + 0] = ex0 * inv;
            wsm[which * 8 + 1] = ex1 * inv;
            wsm[which * 8 + 2] = ex2 * inv;
            wsm[which * 8 + 3] = ex3 * inv;
            wsm[which * 8 + 4] = ex4 * inv;
        }
    }
}

__global__ __launch_bounds__(256) void scan3_kernel(int* degcur, const int* __restrict__ partial,
                                                    int* __restrict__ offsets) {
    __shared__ int sh[256];
    int t = threadIdx.x;
    int base = blockIdx.x * 1024 + t * 4;
    int v[4];
    int ts = 0;
#pragma unroll
    for (int j = 0; j < 4; ++j) {
        int idx = base + j;
        v[j] = (idx < NN) ? degcur[idx] : 0;
        ts += v[j];
    }
    sh[t] = ts;
    __syncthreads();
    for (int off = 1; off < 256; off <<= 1) {
        int x = (t >= off) ? sh[t - off] : 0;
        __syncthreads();
        sh[t] += x;
        __syncthreads();
    }
    int run = sh[t] - ts + partial[blockIdx.x];
#pragma unroll
    for (int j = 0; j < 4; ++j) {
        int idx = base + j;
        if (idx < NN) {
            offsets[idx] = run;
            degcur[idx] = run;  // cursor copy for the fine scatter
            run += v[j];
        }
    }
}

__global__ __launch_bounds__(512) void bucket_init_kernel(const int* __restrict__ offsets,
                                                          int* __restrict__ gcur) {
    int b = blockIdx.x * 512 + threadIdx.x;
    if (b < NBUK) gcur[b] = offsets[b << 8];
}

// Coarse scatter: bin edges into NBUK buckets (dst>>8) with LDS staging so
// global writes are consecutive runs (line-merged) instead of random 4B.
// Payload: src(17b) | dist<<17 (3b) | (dst&255)<<20 (8b).
__global__ __launch_bounds__(512) void coarse_scatter_kernel(const int* __restrict__ src,
                                                             const int* __restrict__ dst,
                                                             const int* __restrict__ dist,
                                                             int* __restrict__ gcur,
                                                             int* __restrict__ coarse) {
    __shared__ int cnt[512];
    __shared__ int scn[512];
    __shared__ int lofs[512];
    __shared__ int gb[512];
    __shared__ int staging[CH];
    __shared__ int tgt[CH];
    int t = threadIdx.x;
    int base = blockIdx.x * CH;

    cnt[t] = 0;
    __syncthreads();

    int val[16], bb[16];
#pragma unroll
    for (int jj = 0; jj < 16; ++jj) {
        int e = base + jj * 512 + t;
        if (e < EE) {
            int d = dst[e];
            int b = d >> 8;
            bb[jj] = b;
            val[jj] = src[e] | (dist[e] << 17) | ((d & 255) << 20);
            atomicAdd(&cnt[b], 1);
        } else {
            bb[jj] = -1;
            val[jj] = 0;
        }
    }
    __syncthreads();

    int c = cnt[t];
    scn[t] = c;
    __syncthreads();
    for (int off = 1; off < 512; off <<= 1) {
        int x = (t >= off) ? scn[t - off] : 0;
        __syncthreads();
        scn[t] += x;
        __syncthreads();
    }
    lofs[t] = scn[t] - c;
    if (t < NBUK && c > 0) gb[t] = atomicAdd(&gcur[t], c);
    cnt[t] = 0;  // reuse as second counter
    __syncthreads();

#pragma unroll
    for (int jj = 0; jj < 16; ++jj) {
        int b = bb[jj];
        if (b >= 0) {
            int pos = atomicAdd(&cnt[b], 1);
            int slot = lofs[b] + pos;
            staging[slot] = val[jj];
            tgt[slot] = gb[b] + pos;
        }
    }
    __syncthreads();

    int total = scn[511];
    for (int j = t; j < total; j += 512) coarse[tgt[j]] = staging[j];
}

// Fine scatter: one block per bucket; reads its coarse segment sequentially,
// scatters within the bucket's (L2-resident) output window to final CSR order.
__global__ __launch_bounds__(512) void fine_scatter_kernel(const int* __restrict__ coarse,
                                                           const int* __restrict__ offsets,
                                                           int* __restrict__ cursor,
                                                           int* __restrict__ sorted) {
    int b = blockIdx.x;
    int gstart = offsets[b << 8];
    int nend = (b + 1) << 8;
    int gend = (nend >= NN) ? EE : offsets[nend];
    for (int idx = gstart + threadIdx.x; idx < gend; idx += 512) {
        int v = coarse[idx];
        int d = (b << 8) | ((v >> 20) & 255);
        int p = atomicAdd(&cursor[d], 1);
        sorted[p] = (v & 0x1FFFF) | (((v >> 17) & 7) << 20);  // src | dist<<20
    }
}

// ---------------------------------------------------------------- converts

__global__ __launch_bounds__(256) void convert_x_kernel(const float* __restrict__ x,
                                                        unsigned short* __restrict__ xb) {
    size_t i = (size_t)(blockIdx.x * 256 + threadIdx.x) * 4;
    float4 v = *(const float4*)(x + i);
    ushort4 o;
    o.x = f2b(v.x);
    o.y = f2b(v.y);
    o.z = f2b(v.z);
    o.w = f2b(v.w);
    *(ushort4*)(xb + i) = o;
}

// transpose + bf16-convert all 7 weights: dst[wi][n][k] = W[wi][k][n]
__global__ __launch_bounds__(256) void prep_w_kernel(const float* W0, const float* W1,
                                                     const float* W2, const float* W3,
                                                     const float* W4, const float* W5,
                                                     const float* W6,
                                                     unsigned short* __restrict__ dst) {
    int idx = blockIdx.x * 256 + threadIdx.x;
    if (idx >= 7 * 16384) return;
    int wi = idx / 16384, r = idx - wi * 16384;
    int n = r & 127, k = r >> 7;
    const float* W = wi == 0 ? W0 : wi == 1 ? W1 : wi == 2 ? W2 : wi == 3 ? W3
                   : wi == 4 ? W4 : wi == 5 ? W5 : W6;
    int ncol = (wi == 6) ? CC : 128;
    float v = (n < ncol) ? W[k * ncol + n] : 0.f;
    dst[wi * 16384 + n * 128 + k] = f2b(v);
}

// ------------------------------------------------------------------- GEMM
// U = (TRANSFORM ? relu(a*Z+d) : Z) @ W + bias  on bf16 inputs, fp32 MFMA accum.

template <int NT, bool TRANSFORM, bool STATS, bool OUTF32>
__global__ __launch_bounds__(256) void mfma_gemm(const unsigned short* __restrict__ Zin,
                                                 const unsigned short* __restrict__ Wt,
                                                 const float* __restrict__ bias, int ncol_real,
                                                 const float* __restrict__ ab,
                                                 void* __restrict__ Uout,
                                                 float* __restrict__ stats) {
    __shared__ unsigned short Zs[128 * 128];
    __shared__ unsigned short Ws[NT * 16 * 128];
    int t = threadIdx.x;
    int m0 = blockIdx.x * 128;
    int c8 = t & 15;  // 16B chunk (8 bf16) within a 128-elem row

    float av[8], dv[8];
    if constexpr (TRANSFORM) {
#pragma unroll
        for (int j = 0; j < 8; ++j) {
            av[j] = ab[c8 * 8 + j];
            dv[j] = ab[128 + c8 * 8 + j];
        }
    }
    // stage A
#pragma unroll
    for (int it = 0; it < 8; ++it) {
        int chunk = it * 256 + t;
        int r = chunk >> 4;
        int gr = m0 + r;
        bf16x8 v = {};
        if (gr < NN) v = *(const bf16x8*)(Zin + (size_t)gr * 128 + c8 * 8);
        if constexpr (TRANSFORM) {
#pragma unroll
            for (int j = 0; j < 8; ++j) {
                float f = fmaxf(0.f, fmaf(av[j], b2f((unsigned short)v[j]), dv[j]));
                v[j] = (short)f2b(f);
            }
        }
        int ks = c8 * 8;
        *(bf16x8*)(&Zs[r * 128 + (ks ^ ((r & 7) << 3))]) = v;
    }
    // stage W^T
    for (int chunk = t; chunk < NT * 16 * 16; chunk += 256) {
        int r = chunk >> 4, cc = chunk & 15;
        bf16x8 v = *(const bf16x8*)(Wt + r * 128 + cc * 8);
        int ks = cc * 8;
        *(bf16x8*)(&Ws[r * 128 + (ks ^ ((r & 7) << 3))]) = v;
    }
    __syncthreads();

    int l = t & 63, w = t >> 6;
    int lr = l & 15, lg = l >> 4;

    f32x4 acc[2][NT];
#pragma unroll
    for (int mt = 0; mt < 2; ++mt)
#pragma unroll
        for (int nt = 0; nt < NT; ++nt) acc[mt][nt] = (f32x4){0.f, 0.f, 0.f, 0.f};

#pragma unroll
    for (int kc = 0; kc < 4; ++kc) {
        int ks = kc * 32 + lg * 8;
        bf16x8 afr[2];
#pragma unroll
        for (int mt = 0; mt < 2; ++mt) {
            int row = w * 32 + mt * 16 + lr;
            afr[mt] = *(const bf16x8*)(&Zs[row * 128 + (ks ^ ((row & 7) << 3))]);
        }
#pragma unroll
        for (int nt = 0; nt < NT; ++nt) {
            int n = nt * 16 + lr;
            bf16x8 bfr = *(const bf16x8*)(&Ws[n * 128 + (ks ^ ((n & 7) << 3))]);
            acc[0][nt] = __builtin_amdgcn_mfma_f32_16x16x32_bf16(afr[0], bfr, acc[0][nt], 0, 0, 0);
            acc[1][nt] = __builtin_amdgcn_mfma_f32_16x16x32_bf16(afr[1], bfr, acc[1][nt], 0, 0, 0);
        }
    }

    float bv[NT];
#pragma unroll
    for (int nt = 0; nt < NT; ++nt) {
        int col = nt * 16 + lr;
        bv[nt] = (col < ncol_real) ? bias[col] : 0.f;
    }
    float s1[NT], s2[NT];
    if constexpr (STATS) {
#pragma unroll
        for (int nt = 0; nt < NT; ++nt) { s1[nt] = 0.f; s2[nt] = 0.f; }
    }

#pragma unroll
    for (int mt = 0; mt < 2; ++mt) {
#pragma unroll
        for (int j = 0; j < 4; ++j) {
            int row = m0 + w * 32 + mt * 16 + lg * 4 + j;
            bool rv = row < NN;
#pragma unroll
            for (int nt = 0; nt < NT; ++nt) {
                float val = acc[mt][nt][j] + bv[nt];
                int col = nt * 16 + lr;
                if constexpr (STATS) {
                    if (rv) { s1[nt] += val; s2[nt] += val * val; }
                }
                if (rv && col < ncol_real) {
                    if constexpr (OUTF32)
                        ((float*)Uout)[(size_t)row * ncol_real + col] = val;
                    else
                        ((unsigned short*)Uout)[(size_t)row * 128 + col] = f2b(val);
                }
            }
        }
    }

    if constexpr (STATS) {
        float* slot = stats + (blockIdx.x & 31) * 256;
#pragma unroll
        for (int nt = 0; nt < NT; ++nt) {
            float a = s1[nt], b = s2[nt];
            a += __shfl_xor(a, 16, 64);
            b += __shfl_xor(b, 16, 64);
            a += __shfl_xor(a, 32, 64);
            b += __shfl_xor(b, 32, 64);
            if (lg == 0) {
                atomicAdd(slot + nt * 16 + lr, a);
                atomicAdd(slot + 128 + nt * 16 + lr, b);
            }
        }
    }
}

// ---------------------------------------------------------------- finalize
// a = g*rsqrt(var+eps); d = beta - a*mean   =>  h = relu(a*u + d)
__global__ void bn_finalize_kernel(const float* __restrict__ stats, const float* __restrict__ g,
                                   const float* __restrict__ beta, float* __restrict__ ab) {
    int ci = threadIdx.x;
    float s = 0.f, s2 = 0.f;
    for (int k = 0; k < 32; ++k) {
        s += stats[k * 256 + ci];
        s2 += stats[k * 256 + 128 + ci];
    }
    float m = s * (1.0f / NN);
    float var = s2 * (1.0f / NN) - m * m;
    float a = g[ci] * rsqrtf(var + 1e-5f);
    ab[ci] = a;
    ab[128 + ci] = beta[ci] - a * m;
}

// -------------------------------------------------------------- aggregation
// Z[i] = h(i) + sum_{e: dst=i} w[dist_e] * h(src_e),  h(j) = relu(a*U[j]+d)
// 128 thr = 4 edge-slots (32 lanes each); lane owns 4 cols via one uint2 load.
__global__ __launch_bounds__(128) void agg_kernel(const unsigned short* __restrict__ U,
                                                  const int* __restrict__ offsets,
                                                  const int* __restrict__ sorted,
                                                  const float* __restrict__ ab,
                                                  const float* __restrict__ wsm,
                                                  unsigned short* __restrict__ Z) {
    __shared__ int ebuf[128];
    __shared__ float wl[8];
    __shared__ f32x4 red[4][32];
    int i = blockIdx.x;
    int t = threadIdx.x;
    int grp = t >> 5;   // edge slot 0..3
    int sl = t & 31;    // cols sl*4 .. sl*4+3
    if (t < KK) wl[t] = wsm[t];

    float a0 = ab[sl * 4 + 0], a1 = ab[sl * 4 + 1], a2 = ab[sl * 4 + 2], a3 = ab[sl * 4 + 3];
    float d0 = ab[128 + sl * 4 + 0], d1 = ab[128 + sl * 4 + 1];
    float d2 = ab[128 + sl * 4 + 2], d3 = ab[128 + sl * 4 + 3];

    int beg = offsets[i], end = offsets[i + 1];
    float acc0 = 0.f, acc1 = 0.f, acc2 = 0.f, acc3 = 0.f;

    for (int base = beg; base < end; base += 128) {
        int n = end - base;
        if (n > 128) n = 128;
        __syncthreads();  // ebuf reuse + wl visibility
        if (t < n) ebuf[t] = sorted[base + t];
        __syncthreads();
        for (int j = grp; j < n; j += 4) {
            int e = ebuf[j];
            unsigned int sidx = (unsigned int)(e & 0xFFFFF);
            float w = wl[e >> 20];
            uint2 u = *(const uint2*)((const char*)U + (sidx << 8) + (sl << 3));
            float h0 = fmaxf(0.f, fmaf(a0, b2f_lo(u.x), d0));
            float h1 = fmaxf(0.f, fmaf(a1, b2f_hi(u.x), d1));
            float h2 = fmaxf(0.f, fmaf(a2, b2f_lo(u.y), d2));
            float h3 = fmaxf(0.f, fmaf(a3, b2f_hi(u.y), d3));
            acc0 = fmaf(w, h0, acc0);
            acc1 = fmaf(w, h1, acc1);
            acc2 = fmaf(w, h2, acc2);
            acc3 = fmaf(w, h3, acc3);
        }
    }
    red[grp][sl] = (f32x4){acc0, acc1, acc2, acc3};
    __syncthreads();

    // final: thread t<64 handles cols 2t,2t+1: sum 4 slots + self term, pack u32
    if (t < 64) {
        const float* rf = (const float*)red;  // [4][128]
        int c0 = t * 2, c1 = t * 2 + 1;
        float s0 = rf[c0] + rf[128 + c0] + rf[256 + c0] + rf[384 + c0];
        float s1 = rf[c1] + rf[128 + c1] + rf[256 + c1] + rf[384 + c1];
        unsigned int ui = *(const unsigned int*)((const char*)U + ((unsigned int)i << 8) + (t << 2));
        float sa0 = ab[c0], sa1 = ab[c1], sd0 = ab[128 + c0], sd1 = ab[128 + c1];
        s0 += fmaxf(0.f, fmaf(sa0, b2f_lo(ui), sd0));
        s1 += fmaxf(0.f, fmaf(sa1, b2f_hi(ui), sd1));
        unsigned int o = (unsigned int)f2b(s0) | ((unsigned int)f2b(s1) << 16);
        *(unsigned int*)((char*)Z + ((unsigned int)i << 8) + (t << 2)) = o;
    }
}

// ------------------------------------------------------------------ launch

extern "C" void kernel_launch(void* const* d_in, const int* in_sizes, int n_in,
                              void* d_out, int out_size, void* d_ws, size_t ws_size,
                              hipStream_t stream) {
    const float* x = (const float*)d_in[0];
    const int* ei = (const int*)d_in[1];
    const int* ed = (const int*)d_in[2];
    const float* Wi = (const float*)d_in[3];
    const float* bi = (const float*)d_in[4];
    const float* gi = (const float*)d_in[5];
    const float* bti = (const float*)d_in[6];
    const float* hc0 = (const float*)d_in[7];
    const float* W0a = (const float*)d_in[8];
    const float* b0a = (const float*)d_in[9];
    const float* g0a = (const float*)d_in[10];
    const float* bt0a = (const float*)d_in[11];
    const float* W0b = (const float*)d_in[12];
    const float* b0b = (const float*)d_in[13];
    const float* g0b = (const float*)d_in[14];
    const float* bt0b = (const float*)d_in[15];
    const float* hc1 = (const float*)d_in[16];
    const float* W1a = (const float*)d_in[17];
    const float* b1a = (const float*)d_in[18];
    const float* g1a = (const float*)d_in[19];
    const float* bt1a = (const float*)d_in[20];
    const float* W1b = (const float*)d_in[21];
    const float* b1b = (const float*)d_in[22];
    const float* g1b = (const float*)d_in[23];
    const float* bt1b = (const float*)d_in[24];
    const float* Wp1 = (const float*)d_in[25];
    const float* bp1 = (const float*)d_in[26];
    const float* gp1 = (const float*)d_in[27];
    const float* btp1 = (const float*)d_in[28];
    const float* Wp2 = (const float*)d_in[29];
    const float* bp2 = (const float*)d_in[30];
    float* out = (float*)d_out;

    const int* srcv = ei;
    const int* dstv = ei + EE;

    // workspace layout (all 16B-aligned)
    unsigned short* bufX = (unsigned short*)d_ws;            // N*128 bf16
    unsigned short* bufA = bufX + (size_t)NN * HH;           // N*128 bf16
    unsigned short* bufB = bufA + (size_t)NN * HH;           // N*128 bf16
    unsigned short* wt = bufB + (size_t)NN * HH;             // 7 * 128*128 bf16 (W^T)
    int* sorted = (int*)(wt + 7 * 16384);                    // E int
    int* coarse = sorted + EE;                               // E int (bucketed)
    int* offsets = coarse + EE;                              // N+1 (padded)
    int* cursor = offsets + (NN + 4);                        // N int
    float* stats = (float*)(cursor + NN);                    // 6 stages * 32 slots * 256
    float* bnab = stats + 6 * 32 * 256;                      // 6 stages * (a[128], d[128])
    float* wsm = bnab + 6 * 256;                             // 2 softmax sets (stride 8)
    int* gcur = (int*)(wsm + 16);                            // NBUK bucket cursors
    int* partial = gcur + ((NBUK + 3) & ~3);                 // scan block partials

    hipMemsetAsync(cursor, 0, (size_t)(NN + 6 * 32 * 256) * sizeof(int), stream);

    // CSR build (reused by both layers)
    hist_kernel<<<(EE + 255) / 256, 256, 0, stream>>>(dstv, cursor);
    int nb = (NN + 1023) / 1024;
    scan1_kernel<<<nb, 256, 0, stream>>>(cursor, partial);
    scan2_kernel<<<1, 128, 0, stream>>>(partial, nb, offsets, hc0, hc1, wsm);
    scan3_kernel<<<nb, 256, 0, stream>>>(cursor, partial, offsets);
    bucket_init_kernel<<<1, 512, 0, stream>>>(offsets, gcur);
    coarse_scatter_kernel<<<(EE + CH - 1) / CH, 512, 0, stream>>>(srcv, dstv, ed, gcur, coarse);
    fine_scatter_kernel<<<NBUK, 512, 0, stream>>>(coarse, offsets, cursor, sorted);

    // bf16 conversions
    convert_x_kernel<<<(NN * HH / 4 + 255) / 256, 256, 0, stream>>>(x, bufX);
    prep_w_kernel<<<(7 * 16384 + 255) / 256, 256, 0, stream>>>(Wi, W0a, W0b, W1a, W1b, Wp1, Wp2, wt);

    int gg = (NN + 127) / 128;

    // initial MLP
    mfma_gemm<8, false, true, false><<<gg, 256, 0, stream>>>(bufX, wt, bi, 128, nullptr, bufA, stats);
    bn_finalize_kernel<<<1, 128, 0, stream>>>(stats, gi, bti, bnab);

    // SPN layer 0
    agg_kernel<<<NN, 128, 0, stream>>>(bufA, offsets, sorted, bnab, wsm, bufB);
    mfma_gemm<8, false, true, false><<<gg, 256, 0, stream>>>(bufB, wt + 16384, b0a, 128, nullptr,
                                                             bufA, stats + 8192);
    bn_finalize_kernel<<<1, 128, 0, stream>>>(stats + 8192, g0a, bt0a, bnab + 256);
    mfma_gemm<8, true, true, false><<<gg, 256, 0, stream>>>(bufA, wt + 2 * 16384, b0b, 128,
                                                            bnab + 256, bufB, stats + 2 * 8192);
    bn_finalize_kernel<<<1, 128, 0, stream>>>(stats + 2 * 8192, g0b, bt0b, bnab + 512);

    // SPN layer 1
    agg_kernel<<<NN, 128, 0, stream>>>(bufB, offsets, sorted, bnab + 512, wsm + 8, bufA);
    mfma_gemm<8, false, true, false><<<gg, 256, 0, stream>>>(bufA, wt + 3 * 16384, b1a, 128,
                                                             nullptr, bufB, stats + 3 * 8192);
    bn_finalize_kernel<<<1, 128, 0, stream>>>(stats + 3 * 8192, g1a, bt1a, bnab + 768);
    mfma_gemm<8, true, true, false><<<gg, 256, 0, stream>>>(bufB, wt + 4 * 16384, b1b, 128,
                                                            bnab + 768, bufA, stats + 4 * 8192);
    bn_finalize_kernel<<<1, 128, 0, stream>>>(stats + 4 * 8192, g1b, bt1b, bnab + 1024);

    // head
    mfma_gemm<8, true, true, false><<<gg, 256, 0, stream>>>(bufA, wt + 5 * 16384, bp1, 128,
                                                            bnab + 1024, bufB, stats + 5 * 8192);
    bn_finalize_kernel<<<1, 128, 0, stream>>>(stats + 5 * 8192, gp1, btp1, bnab + 1280);
    mfma_gemm<3, true, false, true><<<gg, 256, 0, stream>>>(bufB, wt + 6 * 16384, bp2, CC,
                                                            bnab + 1280, out, nullptr);

    (void)in_sizes; (void)n_in; (void)out_size; (void)ws_size;
}

// Round 8
// 726.510 us; speedup vs baseline: 1.0604x; 1.0604x over previous
//
#include <hip/hip_runtime.h>

#define NN 100000
#define EE 3200000
#define HH 128
#define CC 40
#define KK 5
#define NBUK 391   // ceil(NN/256) buckets of 256 nodes
#define CH 8192    // edges per coarse-scatter block

typedef __attribute__((ext_vector_type(8))) short bf16x8;
typedef __attribute__((ext_vector_type(4))) float f32x4;

__device__ inline float b2f(unsigned short u) {
    union { unsigned int i; float f; } c;
    c.i = ((unsigned int)u) << 16;
    return c.f;
}
__device__ inline float b2f_lo(unsigned int u) {
    union { unsigned int i; float f; } c;
    c.i = u << 16;
    return c.f;
}
__device__ inline float b2f_hi(unsigned int u) {
    union { unsigned int i; float f; } c;
    c.i = u & 0xFFFF0000u;
    return c.f;
}
__device__ inline unsigned short f2b(float f) {
    union { float f; unsigned int i; } c;
    c.f = f;
    unsigned int r = c.i + 0x7FFFu + ((c.i >> 16) & 1u);
    return (unsigned short)(r >> 16);
}

// ---------------------------------------------------------------- CSR build

__global__ __launch_bounds__(256) void hist_kernel(const int* __restrict__ dst,
                                                   int* __restrict__ deg) {
    int e = blockIdx.x * 256 + threadIdx.x;
    if (e < EE) atomicAdd(&deg[dst[e]], 1);
}

__global__ __launch_bounds__(256) void scan1_kernel(const int* __restrict__ deg,
                                                    int* __restrict__ partial) {
    __shared__ int sh[256];
    int t = threadIdx.x;
    int base = blockIdx.x * 1024 + t * 4;
    int s = 0;
#pragma unroll
    for (int j = 0; j < 4; ++j) {
        int idx = base + j;
        if (idx < NN) s += deg[idx];
    }
    sh[t] = s;
    __syncthreads();
    for (int off = 128; off > 0; off >>= 1) {
        if (t < off) sh[t] += sh[t + off];
        __syncthreads();
    }
    if (t == 0) partial[blockIdx.x] = sh[0];
}

__global__ void scan2_kernel(int* __restrict__ partial, int nb, int* __restrict__ offsets,
                             const float* __restrict__ hc0, const float* __restrict__ hc1,
                             float* __restrict__ wsm) {
    __shared__ int sh[128];
    int t = threadIdx.x;
    int v = (t < nb) ? partial[t] : 0;
    sh[t] = v;
    __syncthreads();
    for (int off = 1; off < 128; off <<= 1) {
        int x = (t >= off) ? sh[t - off] : 0;
        __syncthreads();
        sh[t] += x;
        __syncthreads();
    }
    if (t < nb) partial[t] = sh[t] - v;  // exclusive block offsets
    if (t == 0) {
        offsets[NN] = EE;
        for (int which = 0; which < 2; ++which) {
            const float* hc = which ? hc1 : hc0;
            float mx = hc[0];
            for (int k = 1; k < KK; ++k) mx = fmaxf(mx, hc[k]);
            float ex0 = expf(hc[0] - mx), ex1 = expf(hc[1] - mx), ex2 = expf(hc[2] - mx);
            float ex3 = expf(hc[3] - mx), ex4 = expf(hc[4] - mx);
            float sum = ex0 + ex1 + ex2 + ex3 + ex4;
            float inv = 1.0f / sum;
            wsm[which * 8 + 0] = ex0 * inv;
            wsm[which * 8 + 1] = ex1 * inv;
            wsm[which * 8 + 2] = ex2 * inv;
            wsm[which * 8 + 3] = ex3 * inv;
            wsm[which * 8 + 4] = ex4 * inv;
        }
    }
}

__global__ __launch_bounds__(256) void scan3_kernel(int* degcur, const int* __restrict__ partial,
                                                    int* __restrict__ offsets) {
    __shared__ int sh[256];
    int t = threadIdx.x;
    int base = blockIdx.x * 1024 + t * 4;
    int v[4];
    int ts = 0;
#pragma unroll
    for (int j = 0; j < 4; ++j) {
        int idx = base + j;
        v[j] = (idx < NN) ? degcur[idx] : 0;
        ts += v[j];
    }
    sh[t] = ts;
    __syncthreads();
    for (int off = 1; off < 256; off <<= 1) {
        int x = (t >= off) ? sh[t - off] : 0;
        __syncthreads();
        sh[t] += x;
        __syncthreads();
    }
    int run = sh[t] - ts + partial[blockIdx.x];
#pragma unroll
    for (int j = 0; j < 4; ++j) {
        int idx = base + j;
        if (idx < NN) {
            offsets[idx] = run;
            degcur[idx] = run;  // cursor copy for the fine scatter
            run += v[j];
        }
    }
}

__global__ __launch_bounds__(512) void bucket_init_kernel(const int* __restrict__ offsets,
                                                          int* __restrict__ gcur) {
    int b = blockIdx.x * 512 + threadIdx.x;
    if (b < NBUK) gcur[b] = offsets[b << 8];
}

// Coarse scatter: bin edges into NBUK buckets (dst>>8) with LDS staging so
// global writes are consecutive runs (line-merged) instead of random 4B.
// Payload: src(17b) | dist<<17 (3b) | (dst&255)<<20 (8b).
__global__ __launch_bounds__(512) void coarse_scatter_kernel(const int* __restrict__ src,
                                                             const int* __restrict__ dst,
                                                             const int* __restrict__ dist,
                                                             int* __restrict__ gcur,
                                                             int* __restrict__ coarse) {
    __shared__ int cnt[512];
    __shared__ int scn[512];
    __shared__ int lofs[512];
    __shared__ int gb[512];
    __shared__ int staging[CH];
    __shared__ int tgt[CH];
    int t = threadIdx.x;
    int base = blockIdx.x * CH;

    cnt[t] = 0;
    __syncthreads();

    int val[16], bb[16];
#pragma unroll
    for (int jj = 0; jj < 16; ++jj) {
        int e = base + jj * 512 + t;
        if (e < EE) {
            int d = dst[e];
            int b = d >> 8;
            bb[jj] = b;
            val[jj] = src[e] | (dist[e] << 17) | ((d & 255) << 20);
            atomicAdd(&cnt[b], 1);
        } else {
            bb[jj] = -1;
            val[jj] = 0;
        }
    }
    __syncthreads();

    int c = cnt[t];
    scn[t] = c;
    __syncthreads();
    for (int off = 1; off < 512; off <<= 1) {
        int x = (t >= off) ? scn[t - off] : 0;
        __syncthreads();
        scn[t] += x;
        __syncthreads();
    }
    lofs[t] = scn[t] - c;
    if (t < NBUK && c > 0) gb[t] = atomicAdd(&gcur[t], c);
    cnt[t] = 0;  // reuse as second counter
    __syncthreads();

#pragma unroll
    for (int jj = 0; jj < 16; ++jj) {
        int b = bb[jj];
        if (b >= 0) {
            int pos = atomicAdd(&cnt[b], 1);
            int slot = lofs[b] + pos;
            staging[slot] = val[jj];
            tgt[slot] = gb[b] + pos;
        }
    }
    __syncthreads();

    int total = scn[511];
    for (int j = t; j < total; j += 512) coarse[tgt[j]] = staging[j];
}

// Fine scatter: one block per bucket; reads its coarse segment sequentially,
// scatters within the bucket's (L2-resident) output window to final CSR order.
__global__ __launch_bounds__(512) void fine_scatter_kernel(const int* __restrict__ coarse,
                                                           const int* __restrict__ offsets,
                                                           int* __restrict__ cursor,
                                                           int* __restrict__ sorted) {
    int b = blockIdx.x;
    int gstart = offsets[b << 8];
    int nend = (b + 1) << 8;
    int gend = (nend >= NN) ? EE : offsets[nend];
    for (int idx = gstart + threadIdx.x; idx < gend; idx += 512) {
        int v = coarse[idx];
        int d = (b << 8) | ((v >> 20) & 255);
        int p = atomicAdd(&cursor[d], 1);
        sorted[p] = (v & 0x1FFFF) | (((v >> 17) & 7) << 20);  // src | dist<<20
    }
}

// ---------------------------------------------------------------- converts

__global__ __launch_bounds__(256) void convert_x_kernel(const float* __restrict__ x,
                                                        unsigned short* __restrict__ xb) {
    size_t i = (size_t)(blockIdx.x * 256 + threadIdx.x) * 4;
    float4 v = *(const float4*)(x + i);
    ushort4 o;
    o.x = f2b(v.x);
    o.y = f2b(v.y);
    o.z = f2b(v.z);
    o.w = f2b(v.w);
    *(ushort4*)(xb + i) = o;
}

// transpose + bf16-convert all 7 weights: dst[wi][n][k] = W[wi][k][n]
__global__ __launch_bounds__(256) void prep_w_kernel(const float* W0, const float* W1,
                                                     const float* W2, const float* W3,
                                                     const float* W4, const float* W5,
                                                     const float* W6,
                                                     unsigned short* __restrict__ dst) {
    int idx = blockIdx.x * 256 + threadIdx.x;
    if (idx >= 7 * 16384) return;
    int wi = idx / 16384, r = idx - wi * 16384;
    int n = r & 127, k = r >> 7;
    const float* W = wi == 0 ? W0 : wi == 1 ? W1 : wi == 2 ? W2 : wi == 3 ? W3
                   : wi == 4 ? W4 : wi == 5 ? W5 : W6;
    int ncol = (wi == 6) ? CC : 128;
    float v = (n < ncol) ? W[k * ncol + n] : 0.f;
    dst[wi * 16384 + n * 128 + k] = f2b(v);
}

// ------------------------------------------------------------------- GEMM
// U = (TRANSFORM ? relu(a*Z+d) : Z) @ W + bias  on bf16 inputs, fp32 MFMA accum.

template <int NT, bool TRANSFORM, bool STATS, bool OUTF32>
__global__ __launch_bounds__(256) void mfma_gemm(const unsigned short* __restrict__ Zin,
                                                 const unsigned short* __restrict__ Wt,
                                                 const float* __restrict__ bias, int ncol_real,
                                                 const float* __restrict__ ab,
                                                 void* __restrict__ Uout,
                                                 float* __restrict__ stats) {
    __shared__ unsigned short Zs[128 * 128];
    __shared__ unsigned short Ws[NT * 16 * 128];
    int t = threadIdx.x;
    int m0 = blockIdx.x * 128;
    int c8 = t & 15;  // 16B chunk (8 bf16) within a 128-elem row

    float av[8], dv[8];
    if constexpr (TRANSFORM) {
#pragma unroll
        for (int j = 0; j < 8; ++j) {
            av[j] = ab[c8 * 8 + j];
            dv[j] = ab[128 + c8 * 8 + j];
        }
    }
    // stage A
#pragma unroll
    for (int it = 0; it < 8; ++it) {
        int chunk = it * 256 + t;
        int r = chunk >> 4;
        int gr = m0 + r;
        bf16x8 v = {};
        if (gr < NN) v = *(const bf16x8*)(Zin + (size_t)gr * 128 + c8 * 8);
        if constexpr (TRANSFORM) {
#pragma unroll
            for (int j = 0; j < 8; ++j) {
                float f = fmaxf(0.f, fmaf(av[j], b2f((unsigned short)v[j]), dv[j]));
                v[j] = (short)f2b(f);
            }
        }
        int ks = c8 * 8;
        *(bf16x8*)(&Zs[r * 128 + (ks ^ ((r & 7) << 3))]) = v;
    }
    // stage W^T
    for (int chunk = t; chunk < NT * 16 * 16; chunk += 256) {
        int r = chunk >> 4, cc = chunk & 15;
        bf16x8 v = *(const bf16x8*)(Wt + r * 128 + cc * 8);
        int ks = cc * 8;
        *(bf16x8*)(&Ws[r * 128 + (ks ^ ((r & 7) << 3))]) = v;
    }
    __syncthreads();

    int l = t & 63, w = t >> 6;
    int lr = l & 15, lg = l >> 4;

    f32x4 acc[2][NT];
#pragma unroll
    for (int mt = 0; mt < 2; ++mt)
#pragma unroll
        for (int nt = 0; nt < NT; ++nt) acc[mt][nt] = (f32x4){0.f, 0.f, 0.f, 0.f};

#pragma unroll
    for (int kc = 0; kc < 4; ++kc) {
        int ks = kc * 32 + lg * 8;
        bf16x8 afr[2];
#pragma unroll
        for (int mt = 0; mt < 2; ++mt) {
            int row = w * 32 + mt * 16 + lr;
            afr[mt] = *(const bf16x8*)(&Zs[row * 128 + (ks ^ ((row & 7) << 3))]);
        }
#pragma unroll
        for (int nt = 0; nt < NT; ++nt) {
            int n = nt * 16 + lr;
            bf16x8 bfr = *(const bf16x8*)(&Ws[n * 128 + (ks ^ ((n & 7) << 3))]);
            acc[0][nt] = __builtin_amdgcn_mfma_f32_16x16x32_bf16(afr[0], bfr, acc[0][nt], 0, 0, 0);
            acc[1][nt] = __builtin_amdgcn_mfma_f32_16x16x32_bf16(afr[1], bfr, acc[1][nt], 0, 0, 0);
        }
    }

    float bv[NT];
#pragma unroll
    for (int nt = 0; nt < NT; ++nt) {
        int col = nt * 16 + lr;
        bv[nt] = (col < ncol_real) ? bias[col] : 0.f;
    }
    float s1[NT], s2[NT];
    if constexpr (STATS) {
#pragma unroll
        for (int nt = 0; nt < NT; ++nt) { s1[nt] = 0.f; s2[nt] = 0.f; }
    }

#pragma unroll
    for (int mt = 0; mt < 2; ++mt) {
#pragma unroll
        for (int j = 0; j < 4; ++j) {
            int row = m0 + w * 32 + mt * 16 + lg * 4 + j;
            bool rv = row < NN;
#pragma unroll
            for (int nt = 0; nt < NT; ++nt) {
                float val = acc[mt][nt][j] + bv[nt];
                int col = nt * 16 + lr;
                if constexpr (STATS) {
                    if (rv) { s1[nt] += val; s2[nt] += val * val; }
                }
                if (rv && col < ncol_real) {
                    if constexpr (OUTF32)
                        ((float*)Uout)[(size_t)row * ncol_real + col] = val;
                    else
                        ((unsigned short*)Uout)[(size_t)row * 128 + col] = f2b(val);
                }
            }
        }
    }

    if constexpr (STATS) {
        float* slot = stats + (blockIdx.x & 31) * 256;
#pragma unroll
        for (int nt = 0; nt < NT; ++nt) {
            float a = s1[nt], b = s2[nt];
            a += __shfl_xor(a, 16, 64);
            b += __shfl_xor(b, 16, 64);
            a += __shfl_xor(a, 32, 64);
            b += __shfl_xor(b, 32, 64);
            if (lg == 0) {
                atomicAdd(slot + nt * 16 + lr, a);
                atomicAdd(slot + 128 + nt * 16 + lr, b);
            }
        }
    }
}

// ---------------------------------------------------------------- finalize
// a = g*rsqrt(var+eps); d = beta - a*mean   =>  h = relu(a*u + d)
__global__ void bn_finalize_kernel(const float* __restrict__ stats, const float* __restrict__ g,
                                   const float* __restrict__ beta, float* __restrict__ ab) {
    int ci = threadIdx.x;
    float s = 0.f, s2 = 0.f;
    for (int k = 0; k < 32; ++k) {
        s += stats[k * 256 + ci];
        s2 += stats[k * 256 + 128 + ci];
    }
    float m = s * (1.0f / NN);
    float var = s2 * (1.0f / NN) - m * m;
    float a = g[ci] * rsqrtf(var + 1e-5f);
    ab[ci] = a;
    ab[128 + ci] = beta[ci] - a * m;
}

// -------------------------------------------------------------- aggregation
// Z[i] = h(i) + sum_{e: dst=i} w[dist_e] * h(src_e),  h(j) = relu(a*U[j]+d)
// 128 thr = 4 edge-slots (32 lanes each); lane owns 4 cols via one uint2 load.
// Inner loop: each slot batches 4 independent gathers (16 outstanding/block)
// before the FMA chain -> hides L2-miss latency (agg was latency-bound at 1).
__global__ __launch_bounds__(128) void agg_kernel(const unsigned short* __restrict__ U,
                                                  const int* __restrict__ offsets,
                                                  const int* __restrict__ sorted,
                                                  const float* __restrict__ ab,
                                                  const float* __restrict__ wsm,
                                                  unsigned short* __restrict__ Z) {
    __shared__ int ebuf[128];
    __shared__ float wl[8];
    __shared__ f32x4 red[4][32];
    int i = blockIdx.x;
    int t = threadIdx.x;
    int grp = t >> 5;   // edge slot 0..3
    int sl = t & 31;    // cols sl*4 .. sl*4+3
    if (t < KK) wl[t] = wsm[t];

    float a0 = ab[sl * 4 + 0], a1 = ab[sl * 4 + 1], a2 = ab[sl * 4 + 2], a3 = ab[sl * 4 + 3];
    float d0 = ab[128 + sl * 4 + 0], d1 = ab[128 + sl * 4 + 1];
    float d2 = ab[128 + sl * 4 + 2], d3 = ab[128 + sl * 4 + 3];

    int beg = offsets[i], end = offsets[i + 1];
    float acc0 = 0.f, acc1 = 0.f, acc2 = 0.f, acc3 = 0.f;

    for (int base = beg; base < end; base += 128) {
        int n = end - base;
        if (n > 128) n = 128;
        __syncthreads();  // ebuf reuse + wl visibility
        if (t < n) ebuf[t] = sorted[base + t];
        __syncthreads();
        int nfull = n & ~15;
        // bulk: slot grp takes edges [j0+4*grp .. j0+4*grp+3] of each 16-stripe
        for (int j0 = grp * 4; j0 < nfull; j0 += 16) {
            uint2 u0, u1, u2, u3;
            float w0, w1, w2, w3;
            {
                int e = ebuf[j0 + 0];
                w0 = wl[e >> 20];
                u0 = *(const uint2*)((const char*)U + ((unsigned int)(e & 0xFFFFF) << 8) + (sl << 3));
            }
            {
                int e = ebuf[j0 + 1];
                w1 = wl[e >> 20];
                u1 = *(const uint2*)((const char*)U + ((unsigned int)(e & 0xFFFFF) << 8) + (sl << 3));
            }
            {
                int e = ebuf[j0 + 2];
                w2 = wl[e >> 20];
                u2 = *(const uint2*)((const char*)U + ((unsigned int)(e & 0xFFFFF) << 8) + (sl << 3));
            }
            {
                int e = ebuf[j0 + 3];
                w3 = wl[e >> 20];
                u3 = *(const uint2*)((const char*)U + ((unsigned int)(e & 0xFFFFF) << 8) + (sl << 3));
            }
            acc0 = fmaf(w0, fmaxf(0.f, fmaf(a0, b2f_lo(u0.x), d0)), acc0);
            acc1 = fmaf(w0, fmaxf(0.f, fmaf(a1, b2f_hi(u0.x), d1)), acc1);
            acc2 = fmaf(w0, fmaxf(0.f, fmaf(a2, b2f_lo(u0.y), d2)), acc2);
            acc3 = fmaf(w0, fmaxf(0.f, fmaf(a3, b2f_hi(u0.y), d3)), acc3);
            acc0 = fmaf(w1, fmaxf(0.f, fmaf(a0, b2f_lo(u1.x), d0)), acc0);
            acc1 = fmaf(w1, fmaxf(0.f, fmaf(a1, b2f_hi(u1.x), d1)), acc1);
            acc2 = fmaf(w1, fmaxf(0.f, fmaf(a2, b2f_lo(u1.y), d2)), acc2);
            acc3 = fmaf(w1, fmaxf(0.f, fmaf(a3, b2f_hi(u1.y), d3)), acc3);
            acc0 = fmaf(w2, fmaxf(0.f, fmaf(a0, b2f_lo(u2.x), d0)), acc0);
            acc1 = fmaf(w2, fmaxf(0.f, fmaf(a1, b2f_hi(u2.x), d1)), acc1);
            acc2 = fmaf(w2, fmaxf(0.f, fmaf(a2, b2f_lo(u2.y), d2)), acc2);
            acc3 = fmaf(w2, fmaxf(0.f, fmaf(a3, b2f_hi(u2.y), d3)), acc3);
            acc0 = fmaf(w3, fmaxf(0.f, fmaf(a0, b2f_lo(u3.x), d0)), acc0);
            acc1 = fmaf(w3, fmaxf(0.f, fmaf(a1, b2f_hi(u3.x), d1)), acc1);
            acc2 = fmaf(w3, fmaxf(0.f, fmaf(a2, b2f_lo(u3.y), d2)), acc2);
            acc3 = fmaf(w3, fmaxf(0.f, fmaf(a3, b2f_hi(u3.y), d3)), acc3);
        }
        // tail: one edge per slot per pass
        for (int j = nfull + grp; j < n; j += 4) {
            int e = ebuf[j];
            unsigned int sidx = (unsigned int)(e & 0xFFFFF);
            float w = wl[e >> 20];
            uint2 u = *(const uint2*)((const char*)U + (sidx << 8) + (sl << 3));
            acc0 = fmaf(w, fmaxf(0.f, fmaf(a0, b2f_lo(u.x), d0)), acc0);
            acc1 = fmaf(w, fmaxf(0.f, fmaf(a1, b2f_hi(u.x), d1)), acc1);
            acc2 = fmaf(w, fmaxf(0.f, fmaf(a2, b2f_lo(u.y), d2)), acc2);
            acc3 = fmaf(w, fmaxf(0.f, fmaf(a3, b2f_hi(u.y), d3)), acc3);
        }
    }
    red[grp][sl] = (f32x4){acc0, acc1, acc2, acc3};
    __syncthreads();

    // final: thread t<64 handles cols 2t,2t+1: sum 4 slots + self term, pack u32
    if (t < 64) {
        const float* rf = (const float*)red;  // [4][128]
        int c0 = t * 2, c1 = t * 2 + 1;
        float s0 = rf[c0] + rf[128 + c0] + rf[256 + c0] + rf[384 + c0];
        float s1 = rf[c1] + rf[128 + c1] + rf[256 + c1] + rf[384 + c1];
        unsigned int ui = *(const unsigned int*)((const char*)U + ((unsigned int)i << 8) + (t << 2));
        float sa0 = ab[c0], sa1 = ab[c1], sd0 = ab[128 + c0], sd1 = ab[128 + c1];
        s0 += fmaxf(0.f, fmaf(sa0, b2f_lo(ui), sd0));
        s1 += fmaxf(0.f, fmaf(sa1, b2f_hi(ui), sd1));
        unsigned int o = (unsigned int)f2b(s0) | ((unsigned int)f2b(s1) << 16);
        *(unsigned int*)((char*)Z + ((unsigned int)i << 8) + (t << 2)) = o;
    }
}

// ------------------------------------------------------------------ launch

extern "C" void kernel_launch(void* const* d_in, const int* in_sizes, int n_in,
                              void* d_out, int out_size, void* d_ws, size_t ws_size,
                              hipStream_t stream) {
    const float* x = (const float*)d_in[0];
    const int* ei = (const int*)d_in[1];
    const int* ed = (const int*)d_in[2];
    const float* Wi = (const float*)d_in[3];
    const float* bi = (const float*)d_in[4];
    const float* gi = (const float*)d_in[5];
    const float* bti = (const float*)d_in[6];
    const float* hc0 = (const float*)d_in[7];
    const float* W0a = (const float*)d_in[8];
    const float* b0a = (const float*)d_in[9];
    const float* g0a = (const float*)d_in[10];
    const float* bt0a = (const float*)d_in[11];
    const float* W0b = (const float*)d_in[12];
    const float* b0b = (const float*)d_in[13];
    const float* g0b = (const float*)d_in[14];
    const float* bt0b = (const float*)d_in[15];
    const float* hc1 = (const float*)d_in[16];
    const float* W1a = (const float*)d_in[17];
    const float* b1a = (const float*)d_in[18];
    const float* g1a = (const float*)d_in[19];
    const float* bt1a = (const float*)d_in[20];
    const float* W1b = (const float*)d_in[21];
    const float* b1b = (const float*)d_in[22];
    const float* g1b = (const float*)d_in[23];
    const float* bt1b = (const float*)d_in[24];
    const float* Wp1 = (const float*)d_in[25];
    const float* bp1 = (const float*)d_in[26];
    const float* gp1 = (const float*)d_in[27];
    const float* btp1 = (const float*)d_in[28];
    const float* Wp2 = (const float*)d_in[29];
    const float* bp2 = (const float*)d_in[30];
    float* out = (float*)d_out;

    const int* srcv = ei;
    const int* dstv = ei + EE;

    // workspace layout (all 16B-aligned)
    unsigned short* bufX = (unsigned short*)d_ws;            // N*128 bf16
    unsigned short* bufA = bufX + (size_t)NN * HH;           // N*128 bf16
    unsigned short* bufB = bufA + (size_t)NN * HH;           // N*128 bf16
    unsigned short* wt = bufB + (size_t)NN * HH;             // 7 * 128*128 bf16 (W^T)
    int* sorted = (int*)(wt + 7 * 16384);                    // E int
    int* coarse = sorted + EE;                               // E int (bucketed)
    int* offsets = coarse + EE;                              // N+1 (padded)
    int* cursor = offsets + (NN + 4);                        // N int
    float* stats = (float*)(cursor + NN);                    // 6 stages * 32 slots * 256
    float* bnab = stats + 6 * 32 * 256;                      // 6 stages * (a[128], d[128])
    float* wsm = bnab + 6 * 256;                             // 2 softmax sets (stride 8)
    int* gcur = (int*)(wsm + 16);                            // NBUK bucket cursors
    int* partial = gcur + ((NBUK + 3) & ~3);                 // scan block partials

    hipMemsetAsync(cursor, 0, (size_t)(NN + 6 * 32 * 256) * sizeof(int), stream);

    // CSR build (reused by both layers)
    hist_kernel<<<(EE + 255) / 256, 256, 0, stream>>>(dstv, cursor);
    int nb = (NN + 1023) / 1024;
    scan1_kernel<<<nb, 256, 0, stream>>>(cursor, partial);
    scan2_kernel<<<1, 128, 0, stream>>>(partial, nb, offsets, hc0, hc1, wsm);
    scan3_kernel<<<nb, 256, 0, stream>>>(cursor, partial, offsets);
    bucket_init_kernel<<<1, 512, 0, stream>>>(offsets, gcur);
    coarse_scatter_kernel<<<(EE + CH - 1) / CH, 512, 0, stream>>>(srcv, dstv, ed, gcur, coarse);
    fine_scatter_kernel<<<NBUK, 512, 0, stream>>>(coarse, offsets, cursor, sorted);

    // bf16 conversions
    convert_x_kernel<<<(NN * HH / 4 + 255) / 256, 256, 0, stream>>>(x, bufX);
    prep_w_kernel<<<(7 * 16384 + 255) / 256, 256, 0, stream>>>(Wi, W0a, W0b, W1a, W1b, Wp1, Wp2, wt);

    int gg = (NN + 127) / 128;

    // initial MLP
    mfma_gemm<8, false, true, false><<<gg, 256, 0, stream>>>(bufX, wt, bi, 128, nullptr, bufA, stats);
    bn_finalize_kernel<<<1, 128, 0, stream>>>(stats, gi, bti, bnab);

    // SPN layer 0
    agg_kernel<<<NN, 128, 0, stream>>>(bufA, offsets, sorted, bnab, wsm, bufB);
    mfma_gemm<8, false, true, false><<<gg, 256, 0, stream>>>(bufB, wt + 16384, b0a, 128, nullptr,
                                                             bufA, stats + 8192);
    bn_finalize_kernel<<<1, 128, 0, stream>>>(stats + 8192, g0a, bt0a, bnab + 256);
    mfma_gemm<8, true, true, false><<<gg, 256, 0, stream>>>(bufA, wt + 2 * 16384, b0b, 128,
                                                            bnab + 256, bufB, stats + 2 * 8192);
    bn_finalize_kernel<<<1, 128, 0, stream>>>(stats + 2 * 8192, g0b, bt0b, bnab + 512);

    // SPN layer 1
    agg_kernel<<<NN, 128, 0, stream>>>(bufB, offsets, sorted, bnab + 512, wsm + 8, bufA);
    mfma_gemm<8, false, true, false><<<gg, 256, 0, stream>>>(bufA, wt + 3 * 16384, b1a, 128,
                                                             nullptr, bufB, stats + 3 * 8192);
    bn_finalize_kernel<<<1, 128, 0, stream>>>(stats + 3 * 8192, g1a, bt1a, bnab + 768);
    mfma_gemm<8, true, true, false><<<gg, 256, 0, stream>>>(bufB, wt + 4 * 16384, b1b, 128,
                                                            bnab + 768, bufA, stats + 4 * 8192);
    bn_finalize_kernel<<<1, 128, 0, stream>>>(stats + 4 * 8192, g1b, bt1b, bnab + 1024);

    // head
    mfma_gemm<8, true, true, false><<<gg, 256, 0, stream>>>(bufA, wt + 5 * 16384, bp1, 128,
                                                            bnab + 1024, bufB, stats + 5 * 8192);
    bn_finalize_kernel<<<1, 128, 0, stream>>>(stats + 5 * 8192, gp1, btp1, bnab + 1280);
    mfma_gemm<3, true, false, true><<<gg, 256, 0, stream>>>(bufB, wt + 6 * 16384, bp2, CC,
                                                            bnab + 1280, out, nullptr);

    (void)in_sizes; (void)n_in; (void)out_size; (void)ws_size;
}

// Round 11
// 572.150 us; speedup vs baseline: 1.3465x; 1.2698x over previous
//
#include <hip/hip_runtime.h>

#define NN 100000
#define EE 3200000
#define HH 128
#define CC 40
#define KK 5
#define NBUK 391   // ceil(NN/256) buckets of 256 nodes
#define CH 8192    // edges per coarse-scatter block
#define CH2 16384  // edges per bucket-hist block

typedef __attribute__((ext_vector_type(8))) short bf16x8;
typedef __attribute__((ext_vector_type(4))) float f32x4;

__device__ inline float b2f(unsigned short u) {
    union { unsigned int i; float f; } c;
    c.i = ((unsigned int)u) << 16;
    return c.f;
}
__device__ inline float b2f_lo(unsigned int u) {
    union { unsigned int i; float f; } c;
    c.i = u << 16;
    return c.f;
}
__device__ inline float b2f_hi(unsigned int u) {
    union { unsigned int i; float f; } c;
    c.i = u & 0xFFFF0000u;
    return c.f;
}
__device__ inline unsigned short f2b(float f) {
    union { float f; unsigned int i; } c;
    c.f = f;
    unsigned int r = c.i + 0x7FFFu + ((c.i >> 16) & 1u);
    return (unsigned short)(r >> 16);
}

// ---------------------------------------------------------------- CSR build
// Per-bucket degrees via LDS-aggregated histogram (391 buckets of 256 nodes).
__global__ __launch_bounds__(512) void bucket_hist_kernel(const int* __restrict__ dst,
                                                          int* __restrict__ bdeg) {
    __shared__ int h[512];
    int t = threadIdx.x;
    h[t] = 0;
    __syncthreads();
    int base = blockIdx.x * CH2;
    int end = base + CH2;
    if (end > EE) end = EE;
    for (int e = base + t; e < end; e += 512) atomicAdd(&h[dst[e] >> 8], 1);
    __syncthreads();
    int v = h[t];
    if (v > 0) atomicAdd(&bdeg[t], v);
}

// Single block: scan bucket degrees -> bucket bases + coarse cursors;
// also offsets[NN]=EE and the two hop-weight softmaxes.
__global__ void bucket_scan_kernel(const int* __restrict__ bdeg, int* __restrict__ bbase,
                                   int* __restrict__ gcur, int* __restrict__ offsets,
                                   const float* __restrict__ hc0, const float* __restrict__ hc1,
                                   float* __restrict__ wsm) {
    __shared__ int sh[512];
    int t = threadIdx.x;
    int v = (t < NBUK) ? bdeg[t] : 0;
    sh[t] = v;
    __syncthreads();
    for (int off = 1; off < 512; off <<= 1) {
        int x = (t >= off) ? sh[t - off] : 0;
        __syncthreads();
        sh[t] += x;
        __syncthreads();
    }
    if (t < NBUK) {
        int b = sh[t] - v;  // exclusive prefix
        bbase[t] = b;
        gcur[t] = b;
    }
    if (t == 0) {
        bbase[NBUK] = EE;
        offsets[NN] = EE;
        for (int which = 0; which < 2; ++which) {
            const float* hc = which ? hc1 : hc0;
            float mx = hc[0];
            for (int k = 1; k < KK; ++k) mx = fmaxf(mx, hc[k]);
            float ex0 = expf(hc[0] - mx), ex1 = expf(hc[1] - mx), ex2 = expf(hc[2] - mx);
            float ex3 = expf(hc[3] - mx), ex4 = expf(hc[4] - mx);
            float inv = 1.0f / (ex0 + ex1 + ex2 + ex3 + ex4);
            wsm[which * 8 + 0] = ex0 * inv;
            wsm[which * 8 + 1] = ex1 * inv;
            wsm[which * 8 + 2] = ex2 * inv;
            wsm[which * 8 + 3] = ex3 * inv;
            wsm[which * 8 + 4] = ex4 * inv;
        }
    }
}

// Coarse scatter: bin edges into NBUK buckets (dst>>8) with LDS staging so
// global writes are consecutive runs (line-merged) instead of random 4B.
// Payload: src(17b) | dist<<17 (3b) | (dst&255)<<20 (8b).
__global__ __launch_bounds__(512) void coarse_scatter_kernel(const int* __restrict__ src,
                                                             const int* __restrict__ dst,
                                                             const int* __restrict__ dist,
                                                             int* __restrict__ gcur,
                                                             int* __restrict__ coarse) {
    __shared__ int cnt[512];
    __shared__ int scn[512];
    __shared__ int lofs[512];
    __shared__ int gb[512];
    __shared__ int staging[CH];
    __shared__ int tgt[CH];
    int t = threadIdx.x;
    int base = blockIdx.x * CH;

    cnt[t] = 0;
    __syncthreads();

    int val[16], bb[16];
#pragma unroll
    for (int jj = 0; jj < 16; ++jj) {
        int e = base + jj * 512 + t;
        if (e < EE) {
            int d = dst[e];
            int b = d >> 8;
            bb[jj] = b;
            val[jj] = src[e] | (dist[e] << 17) | ((d & 255) << 20);
            atomicAdd(&cnt[b], 1);
        } else {
            bb[jj] = -1;
            val[jj] = 0;
        }
    }
    __syncthreads();

    int c = cnt[t];
    scn[t] = c;
    __syncthreads();
    for (int off = 1; off < 512; off <<= 1) {
        int x = (t >= off) ? scn[t - off] : 0;
        __syncthreads();
        scn[t] += x;
        __syncthreads();
    }
    lofs[t] = scn[t] - c;
    if (t < NBUK && c > 0) gb[t] = atomicAdd(&gcur[t], c);
    cnt[t] = 0;  // reuse as second counter
    __syncthreads();

#pragma unroll
    for (int jj = 0; jj < 16; ++jj) {
        int b = bb[jj];
        if (b >= 0) {
            int pos = atomicAdd(&cnt[b], 1);
            int slot = lofs[b] + pos;
            staging[slot] = val[jj];
            tgt[slot] = gb[b] + pos;
        }
    }
    __syncthreads();

    int total = scn[511];
    for (int j = t; j < total; j += 512) coarse[tgt[j]] = staging[j];
}

// Fine scatter v2: one block per bucket. Pass A: LDS histogram of the 256
// in-bucket node slots + LDS scan -> per-node CSR offsets (written to global).
// Pass B: scatter via LDS cursors. No global per-node atomics anywhere.
__global__ __launch_bounds__(512) void fine_scatter_kernel(const int* __restrict__ coarse,
                                                           const int* __restrict__ bbase,
                                                           int* __restrict__ offsets,
                                                           int* __restrict__ sorted) {
    __shared__ int cnt[256];
    __shared__ int scn[256];
    __shared__ int cur[256];
    int b = blockIdx.x;
    int t = threadIdx.x;
    if (t < 256) cnt[t] = 0;
    __syncthreads();
    int sb = bbase[b], se = bbase[b + 1];
    for (int idx = sb + t; idx < se; idx += 512)
        atomicAdd(&cnt[(coarse[idx] >> 20) & 255], 1);
    __syncthreads();
    int c = (t < 256) ? cnt[t] : 0;
    if (t < 256) scn[t] = c;
    __syncthreads();
    for (int off = 1; off < 256; off <<= 1) {
        int x = 0;
        if (t < 256 && t >= off) x = scn[t - off];
        __syncthreads();
        if (t < 256) scn[t] += x;
        __syncthreads();
    }
    if (t < 256) {
        int pos = sb + scn[t] - c;  // exclusive prefix within bucket
        int node = (b << 8) + t;
        if (node < NN) offsets[node] = pos;
        cur[t] = pos;
    }
    __syncthreads();
    for (int idx = sb + t; idx < se; idx += 512) {
        int v = coarse[idx];
        int p = atomicAdd(&cur[(v >> 20) & 255], 1);
        sorted[p] = (v & 0x1FFFF) | (((v >> 17) & 7) << 20);  // src | dist<<20
    }
}

// ---------------------------------------------------------------- converts

__global__ __launch_bounds__(256) void convert_x_kernel(const float* __restrict__ x,
                                                        unsigned short* __restrict__ xb) {
    size_t i = (size_t)(blockIdx.x * 256 + threadIdx.x) * 4;
    float4 v = *(const float4*)(x + i);
    ushort4 o;
    o.x = f2b(v.x);
    o.y = f2b(v.y);
    o.z = f2b(v.z);
    o.w = f2b(v.w);
    *(ushort4*)(xb + i) = o;
}

// transpose + bf16-convert all 7 weights: dst[wi][n][k] = W[wi][k][n]
__global__ __launch_bounds__(256) void prep_w_kernel(const float* W0, const float* W1,
                                                     const float* W2, const float* W3,
                                                     const float* W4, const float* W5,
                                                     const float* W6,
                                                     unsigned short* __restrict__ dst) {
    int idx = blockIdx.x * 256 + threadIdx.x;
    if (idx >= 7 * 16384) return;
    int wi = idx / 16384, r = idx - wi * 16384;
    int n = r & 127, k = r >> 7;
    const float* W = wi == 0 ? W0 : wi == 1 ? W1 : wi == 2 ? W2 : wi == 3 ? W3
                   : wi == 4 ? W4 : wi == 5 ? W5 : W6;
    int ncol = (wi == 6) ? CC : 128;
    float v = (n < ncol) ? W[k * ncol + n] : 0.f;
    dst[wi * 16384 + n * 128 + k] = f2b(v);
}

// ------------------------------------------------------------------- GEMM
// U = (TRANSFORM ? relu(a*Z+d) : Z) @ W + bias  on bf16 inputs, fp32 MFMA accum.

template <int NT, bool TRANSFORM, bool STATS, bool OUTF32>
__global__ __launch_bounds__(256) void mfma_gemm(const unsigned short* __restrict__ Zin,
                                                 const unsigned short* __restrict__ Wt,
                                                 const float* __restrict__ bias, int ncol_real,
                                                 const float* __restrict__ ab,
                                                 void* __restrict__ Uout,
                                                 float* __restrict__ stats) {
    __shared__ unsigned short Zs[128 * 128];
    __shared__ unsigned short Ws[NT * 16 * 128];
    int t = threadIdx.x;
    int m0 = blockIdx.x * 128;
    int c8 = t & 15;  // 16B chunk (8 bf16) within a 128-elem row

    float av[8], dv[8];
    if constexpr (TRANSFORM) {
#pragma unroll
        for (int j = 0; j < 8; ++j) {
            av[j] = ab[c8 * 8 + j];
            dv[j] = ab[128 + c8 * 8 + j];
        }
    }
    // stage A
#pragma unroll
    for (int it = 0; it < 8; ++it) {
        int chunk = it * 256 + t;
        int r = chunk >> 4;
        int gr = m0 + r;
        bf16x8 v = {};
        if (gr < NN) v = *(const bf16x8*)(Zin + (size_t)gr * 128 + c8 * 8);
        if constexpr (TRANSFORM) {
#pragma unroll
            for (int j = 0; j < 8; ++j) {
                float f = fmaxf(0.f, fmaf(av[j], b2f((unsigned short)v[j]), dv[j]));
                v[j] = (short)f2b(f);
            }
        }
        int ks = c8 * 8;
        *(bf16x8*)(&Zs[r * 128 + (ks ^ ((r & 7) << 3))]) = v;
    }
    // stage W^T
    for (int chunk = t; chunk < NT * 16 * 16; chunk += 256) {
        int r = chunk >> 4, cc = chunk & 15;
        bf16x8 v = *(const bf16x8*)(Wt + r * 128 + cc * 8);
        int ks = cc * 8;
        *(bf16x8*)(&Ws[r * 128 + (ks ^ ((r & 7) << 3))]) = v;
    }
    __syncthreads();

    int l = t & 63, w = t >> 6;
    int lr = l & 15, lg = l >> 4;

    f32x4 acc[2][NT];
#pragma unroll
    for (int mt = 0; mt < 2; ++mt)
#pragma unroll
        for (int nt = 0; nt < NT; ++nt) acc[mt][nt] = (f32x4){0.f, 0.f, 0.f, 0.f};

#pragma unroll
    for (int kc = 0; kc < 4; ++kc) {
        int ks = kc * 32 + lg * 8;
        bf16x8 afr[2];
#pragma unroll
        for (int mt = 0; mt < 2; ++mt) {
            int row = w * 32 + mt * 16 + lr;
            afr[mt] = *(const bf16x8*)(&Zs[row * 128 + (ks ^ ((row & 7) << 3))]);
        }
#pragma unroll
        for (int nt = 0; nt < NT; ++nt) {
            int n = nt * 16 + lr;
            bf16x8 bfr = *(const bf16x8*)(&Ws[n * 128 + (ks ^ ((n & 7) << 3))]);
            acc[0][nt] = __builtin_amdgcn_mfma_f32_16x16x32_bf16(afr[0], bfr, acc[0][nt], 0, 0, 0);
            acc[1][nt] = __builtin_amdgcn_mfma_f32_16x16x32_bf16(afr[1], bfr, acc[1][nt], 0, 0, 0);
        }
    }

    float bv[NT];
#pragma unroll
    for (int nt = 0; nt < NT; ++nt) {
        int col = nt * 16 + lr;
        bv[nt] = (col < ncol_real) ? bias[col] : 0.f;
    }
    float s1[NT], s2[NT];
    if constexpr (STATS) {
#pragma unroll
        for (int nt = 0; nt < NT; ++nt) { s1[nt] = 0.f; s2[nt] = 0.f; }
    }

#pragma unroll
    for (int mt = 0; mt < 2; ++mt) {
#pragma unroll
        for (int j = 0; j < 4; ++j) {
            int row = m0 + w * 32 + mt * 16 + lg * 4 + j;
            bool rv = row < NN;
#pragma unroll
            for (int nt = 0; nt < NT; ++nt) {
                float val = acc[mt][nt][j] + bv[nt];
                int col = nt * 16 + lr;
                if constexpr (STATS) {
                    if (rv) { s1[nt] += val; s2[nt] += val * val; }
                }
                if (rv && col < ncol_real) {
                    if constexpr (OUTF32)
                        ((float*)Uout)[(size_t)row * ncol_real + col] = val;
                    else
                        ((unsigned short*)Uout)[(size_t)row * 128 + col] = f2b(val);
                }
            }
        }
    }

    if constexpr (STATS) {
        float* slot = stats + (blockIdx.x & 31) * 256;
#pragma unroll
        for (int nt = 0; nt < NT; ++nt) {
            float a = s1[nt], b = s2[nt];
            a += __shfl_xor(a, 16, 64);
            b += __shfl_xor(b, 16, 64);
            a += __shfl_xor(a, 32, 64);
            b += __shfl_xor(b, 32, 64);
            if (lg == 0) {
                atomicAdd(slot + nt * 16 + lr, a);
                atomicAdd(slot + 128 + nt * 16 + lr, b);
            }
        }
    }
}

// ---------------------------------------------------------------- finalize
// a = g*rsqrt(var+eps); d = beta - a*mean   =>  h = relu(a*u + d)
__global__ void bn_finalize_kernel(const float* __restrict__ stats, const float* __restrict__ g,
                                   const float* __restrict__ beta, float* __restrict__ ab) {
    int ci = threadIdx.x;
    float s = 0.f, s2 = 0.f;
    for (int k = 0; k < 32; ++k) {
        s += stats[k * 256 + ci];
        s2 += stats[k * 256 + 128 + ci];
    }
    float m = s * (1.0f / NN);
    float var = s2 * (1.0f / NN) - m * m;
    float a = g[ci] * rsqrtf(var + 1e-5f);
    ab[ci] = a;
    ab[128 + ci] = beta[ci] - a * m;
}

// -------------------------------------------------------------- aggregation
// Z[i] = h(i) + sum_{e: dst=i} w[dist_e] * h(src_e),  h(j) = relu(a*U[j]+d)
// 128 thr = 4 edge-slots (32 lanes each); lane owns 4 cols via one uint2 load.
// Each slot batches 8 independent gathers (32 outstanding/block) to hide
// L2-miss latency before the FMA chain.
__global__ __launch_bounds__(128) void agg_kernel(const unsigned short* __restrict__ U,
                                                  const int* __restrict__ offsets,
                                                  const int* __restrict__ sorted,
                                                  const float* __restrict__ ab,
                                                  const float* __restrict__ wsm,
                                                  unsigned short* __restrict__ Z) {
    __shared__ int ebuf[128];
    __shared__ float wl[8];
    __shared__ f32x4 red[4][32];
    int i = blockIdx.x;
    int t = threadIdx.x;
    int grp = t >> 5;   // edge slot 0..3
    int sl = t & 31;    // cols sl*4 .. sl*4+3
    if (t < KK) wl[t] = wsm[t];

    float a0 = ab[sl * 4 + 0], a1 = ab[sl * 4 + 1], a2 = ab[sl * 4 + 2], a3 = ab[sl * 4 + 3];
    float d0 = ab[128 + sl * 4 + 0], d1 = ab[128 + sl * 4 + 1];
    float d2 = ab[128 + sl * 4 + 2], d3 = ab[128 + sl * 4 + 3];

    int beg = offsets[i], end = offsets[i + 1];
    float acc0 = 0.f, acc1 = 0.f, acc2 = 0.f, acc3 = 0.f;

    for (int base = beg; base < end; base += 128) {
        int n = end - base;
        if (n > 128) n = 128;
        __syncthreads();  // ebuf reuse + wl visibility
        if (t < n) ebuf[t] = sorted[base + t];
        __syncthreads();
        int nfull = n & ~31;
        // bulk: slot grp takes edges [j0+8*grp .. j0+8*grp+7] of each 32-stripe
        for (int j0 = grp * 8; j0 < nfull; j0 += 32) {
            uint2 uu[8];
            float ww[8];
#pragma unroll
            for (int k = 0; k < 8; ++k) {
                int e = ebuf[j0 + k];
                ww[k] = wl[e >> 20];
                uu[k] = *(const uint2*)((const char*)U +
                                        ((unsigned int)(e & 0xFFFFF) << 8) + (sl << 3));
            }
#pragma unroll
            for (int k = 0; k < 8; ++k) {
                acc0 = fmaf(ww[k], fmaxf(0.f, fmaf(a0, b2f_lo(uu[k].x), d0)), acc0);
                acc1 = fmaf(ww[k], fmaxf(0.f, fmaf(a1, b2f_hi(uu[k].x), d1)), acc1);
                acc2 = fmaf(ww[k], fmaxf(0.f, fmaf(a2, b2f_lo(uu[k].y), d2)), acc2);
                acc3 = fmaf(ww[k], fmaxf(0.f, fmaf(a3, b2f_hi(uu[k].y), d3)), acc3);
            }
        }
        // tail: one edge per slot per pass
        for (int j = nfull + grp; j < n; j += 4) {
            int e = ebuf[j];
            unsigned int sidx = (unsigned int)(e & 0xFFFFF);
            float w = wl[e >> 20];
            uint2 u = *(const uint2*)((const char*)U + (sidx << 8) + (sl << 3));
            acc0 = fmaf(w, fmaxf(0.f, fmaf(a0, b2f_lo(u.x), d0)), acc0);
            acc1 = fmaf(w, fmaxf(0.f, fmaf(a1, b2f_hi(u.x), d1)), acc1);
            acc2 = fmaf(w, fmaxf(0.f, fmaf(a2, b2f_lo(u.y), d2)), acc2);
            acc3 = fmaf(w, fmaxf(0.f, fmaf(a3, b2f_hi(u.y), d3)), acc3);
        }
    }
    red[grp][sl] = (f32x4){acc0, acc1, acc2, acc3};
    __syncthreads();

    // final: thread t<64 handles cols 2t,2t+1: sum 4 slots + self term, pack u32
    if (t < 64) {
        const float* rf = (const float*)red;  // [4][128]
        int c0 = t * 2, c1 = t * 2 + 1;
        float s0 = rf[c0] + rf[128 + c0] + rf[256 + c0] + rf[384 + c0];
        float s1 = rf[c1] + rf[128 + c1] + rf[256 + c1] + rf[384 + c1];
        unsigned int ui = *(const unsigned int*)((const char*)U + ((unsigned int)i << 8) + (t << 2));
        float sa0 = ab[c0], sa1 = ab[c1], sd0 = ab[128 + c0], sd1 = ab[128 + c1];
        s0 += fmaxf(0.f, fmaf(sa0, b2f_lo(ui), sd0));
        s1 += fmaxf(0.f, fmaf(sa1, b2f_hi(ui), sd1));
        unsigned int o = (unsigned int)f2b(s0) | ((unsigned int)f2b(s1) << 16);
        *(unsigned int*)((char*)Z + ((unsigned int)i << 8) + (t << 2)) = o;
    }
}

// ------------------------------------------------------------------ launch

extern "C" void kernel_launch(void* const* d_in, const int* in_sizes, int n_in,
                              void* d_out, int out_size, void* d_ws, size_t ws_size,
                              hipStream_t stream) {
    const float* x = (const float*)d_in[0];
    const int* ei = (const int*)d_in[1];
    const int* ed = (const int*)d_in[2];
    const float* Wi = (const float*)d_in[3];
    const float* bi = (const float*)d_in[4];
    const float* gi = (const float*)d_in[5];
    const float* bti = (const float*)d_in[6];
    const float* hc0 = (const float*)d_in[7];
    const float* W0a = (const float*)d_in[8];
    const float* b0a = (const float*)d_in[9];
    const float* g0a = (const float*)d_in[10];
    const float* bt0a = (const float*)d_in[11];
    const float* W0b = (const float*)d_in[12];
    const float* b0b = (const float*)d_in[13];
    const float* g0b = (const float*)d_in[14];
    const float* bt0b = (const float*)d_in[15];
    const float* hc1 = (const float*)d_in[16];
    const float* W1a = (const float*)d_in[17];
    const float* b1a = (const float*)d_in[18];
    const float* g1a = (const float*)d_in[19];
    const float* bt1a = (const float*)d_in[20];
    const float* W1b = (const float*)d_in[21];
    const float* b1b = (const float*)d_in[22];
    const float* g1b = (const float*)d_in[23];
    const float* bt1b = (const float*)d_in[24];
    const float* Wp1 = (const float*)d_in[25];
    const float* bp1 = (const float*)d_in[26];
    const float* gp1 = (const float*)d_in[27];
    const float* btp1 = (const float*)d_in[28];
    const float* Wp2 = (const float*)d_in[29];
    const float* bp2 = (const float*)d_in[30];
    float* out = (float*)d_out;

    const int* srcv = ei;
    const int* dstv = ei + EE;

    // workspace layout (all 16B-aligned)
    unsigned short* bufX = (unsigned short*)d_ws;            // N*128 bf16
    unsigned short* bufA = bufX + (size_t)NN * HH;           // N*128 bf16
    unsigned short* bufB = bufA + (size_t)NN * HH;           // N*128 bf16
    unsigned short* wt = bufB + (size_t)NN * HH;             // 7 * 128*128 bf16 (W^T)
    int* sorted = (int*)(wt + 7 * 16384);                    // E int
    int* coarse = sorted + EE;                               // E int (bucketed)
    int* offsets = coarse + EE;                              // N+1 (padded)
    float* stats = (float*)(offsets + NN + 4);               // 6 stages * 32 slots * 256
    float* bnab = stats + 6 * 32 * 256;                      // 6 stages * (a[128], d[128])
    float* wsm = bnab + 6 * 256;                             // 2 softmax sets (stride 8)
    int* gcur = (int*)(wsm + 16);                            // NBUK coarse cursors (512)
    int* bdeg = gcur + 512;                                  // NBUK bucket degrees (512)
    int* bbase = bdeg + 512;                                 // NBUK+1 bucket bases

    // zero stats accumulators + bucket degrees
    hipMemsetAsync(stats, 0, (size_t)(6 * 32 * 256) * sizeof(float), stream);
    hipMemsetAsync(bdeg, 0, 512 * sizeof(int), stream);

    // CSR build (reused by both layers)
    bucket_hist_kernel<<<(EE + CH2 - 1) / CH2, 512, 0, stream>>>(dstv, bdeg);
    bucket_scan_kernel<<<1, 512, 0, stream>>>(bdeg, bbase, gcur, offsets, hc0, hc1, wsm);
    coarse_scatter_kernel<<<(EE + CH - 1) / CH, 512, 0, stream>>>(srcv, dstv, ed, gcur, coarse);
    fine_scatter_kernel<<<NBUK, 512, 0, stream>>>(coarse, bbase, offsets, sorted);

    // bf16 conversions
    convert_x_kernel<<<(NN * HH / 4 + 255) / 256, 256, 0, stream>>>(x, bufX);
    prep_w_kernel<<<(7 * 16384 + 255) / 256, 256, 0, stream>>>(Wi, W0a, W0b, W1a, W1b, Wp1, Wp2, wt);

    int gg = (NN + 127) / 128;

    // initial MLP
    mfma_gemm<8, false, true, false><<<gg, 256, 0, stream>>>(bufX, wt, bi, 128, nullptr, bufA, stats);
    bn_finalize_kernel<<<1, 128, 0, stream>>>(stats, gi, bti, bnab);

    // SPN layer 0
    agg_kernel<<<NN, 128, 0, stream>>>(bufA, offsets, sorted, bnab, wsm, bufB);
    mfma_gemm<8, false, true, false><<<gg, 256, 0, stream>>>(bufB, wt + 16384, b0a, 128, nullptr,
                                                             bufA, stats + 8192);
    bn_finalize_kernel<<<1, 128, 0, stream>>>(stats + 8192, g0a, bt0a, bnab + 256);
    mfma_gemm<8, true, true, false><<<gg, 256, 0, stream>>>(bufA, wt + 2 * 16384, b0b, 128,
                                                            bnab + 256, bufB, stats + 2 * 8192);
    bn_finalize_kernel<<<1, 128, 0, stream>>>(stats + 2 * 8192, g0b, bt0b, bnab + 512);

    // SPN layer 1
    agg_kernel<<<NN, 128, 0, stream>>>(bufB, offsets, sorted, bnab + 512, wsm + 8, bufA);
    mfma_gemm<8, false, true, false><<<gg, 256, 0, stream>>>(bufA, wt + 3 * 16384, b1a, 128,
                                                             nullptr, bufB, stats + 3 * 8192);
    bn_finalize_kernel<<<1, 128, 0, stream>>>(stats + 3 * 8192, g1a, bt1a, bnab + 768);
    mfma_gemm<8, true, true, false><<<gg, 256, 0, stream>>>(bufB, wt + 4 * 16384, b1b, 128,
                                                            bnab + 768, bufA, stats + 4 * 8192);
    bn_finalize_kernel<<<1, 128, 0, stream>>>(stats + 4 * 8192, g1b, bt1b, bnab + 1024);

    // head
    mfma_gemm<8, true, true, false><<<gg, 256, 0, stream>>>(bufA, wt + 5 * 16384, bp1, 128,
                                                            bnab + 1024, bufB, stats + 5 * 8192);
    bn_finalize_kernel<<<1, 128, 0, stream>>>(stats + 5 * 8192, gp1, btp1, bnab + 1280);
    mfma_gemm<3, true, false, true><<<gg, 256, 0, stream>>>(bufB, wt + 6 * 16384, bp2, CC,
                                                            bnab + 1280, out, nullptr);

    (void)in_sizes; (void)n_in; (void)out_size; (void)ws_size;
}

// Round 12
// 557.770 us; speedup vs baseline: 1.3812x; 1.0258x over previous
//
#include <hip/hip_runtime.h>

#define NN 100000
#define EE 3200000
#define HH 128
#define CC 40
#define KK 5
#define NBUK 391   // ceil(NN/256) buckets of 256 nodes
#define CH 8192    // edges per coarse-scatter block
#define CH2 16384  // edges per bucket-hist block

typedef __attribute__((ext_vector_type(8))) short bf16x8;
typedef __attribute__((ext_vector_type(4))) float f32x4;

__device__ inline float b2f(unsigned short u) {
    union { unsigned int i; float f; } c;
    c.i = ((unsigned int)u) << 16;
    return c.f;
}
__device__ inline float b2f_lo(unsigned int u) {
    union { unsigned int i; float f; } c;
    c.i = u << 16;
    return c.f;
}
__device__ inline float b2f_hi(unsigned int u) {
    union { unsigned int i; float f; } c;
    c.i = u & 0xFFFF0000u;
    return c.f;
}
__device__ inline unsigned short f2b(float f) {
    union { float f; unsigned int i; } c;
    c.f = f;
    unsigned int r = c.i + 0x7FFFu + ((c.i >> 16) & 1u);
    return (unsigned short)(r >> 16);
}

// ---------------------------------------------------------------- CSR build
// Per-bucket degrees via LDS-aggregated histogram (391 buckets of 256 nodes).
__global__ __launch_bounds__(512) void bucket_hist_kernel(const int* __restrict__ dst,
                                                          int* __restrict__ bdeg) {
    __shared__ int h[512];
    int t = threadIdx.x;
    h[t] = 0;
    __syncthreads();
    int base = blockIdx.x * CH2;
    int end = base + CH2;
    if (end > EE) end = EE;
    for (int e = base + t; e < end; e += 512) atomicAdd(&h[dst[e] >> 8], 1);
    __syncthreads();
    int v = h[t];
    if (v > 0) atomicAdd(&bdeg[t], v);
}

// Single block: scan bucket degrees -> bucket bases + coarse cursors;
// also offsets[NN]=EE and the two hop-weight softmaxes.
__global__ void bucket_scan_kernel(const int* __restrict__ bdeg, int* __restrict__ bbase,
                                   int* __restrict__ gcur, int* __restrict__ offsets,
                                   const float* __restrict__ hc0, const float* __restrict__ hc1,
                                   float* __restrict__ wsm) {
    __shared__ int sh[512];
    int t = threadIdx.x;
    int v = (t < NBUK) ? bdeg[t] : 0;
    sh[t] = v;
    __syncthreads();
    for (int off = 1; off < 512; off <<= 1) {
        int x = (t >= off) ? sh[t - off] : 0;
        __syncthreads();
        sh[t] += x;
        __syncthreads();
    }
    if (t < NBUK) {
        int b = sh[t] - v;  // exclusive prefix
        bbase[t] = b;
        gcur[t] = b;
    }
    if (t == 0) {
        bbase[NBUK] = EE;
        offsets[NN] = EE;
        for (int which = 0; which < 2; ++which) {
            const float* hc = which ? hc1 : hc0;
            float mx = hc[0];
            for (int k = 1; k < KK; ++k) mx = fmaxf(mx, hc[k]);
            float ex0 = expf(hc[0] - mx), ex1 = expf(hc[1] - mx), ex2 = expf(hc[2] - mx);
            float ex3 = expf(hc[3] - mx), ex4 = expf(hc[4] - mx);
            float inv = 1.0f / (ex0 + ex1 + ex2 + ex3 + ex4);
            wsm[which * 8 + 0] = ex0 * inv;
            wsm[which * 8 + 1] = ex1 * inv;
            wsm[which * 8 + 2] = ex2 * inv;
            wsm[which * 8 + 3] = ex3 * inv;
            wsm[which * 8 + 4] = ex4 * inv;
        }
    }
}

// Coarse scatter: bin edges into NBUK buckets (dst>>8) with LDS staging so
// global writes are consecutive runs (line-merged) instead of random 4B.
// Payload: src(17b) | dist<<17 (3b) | (dst&255)<<20 (8b).
__global__ __launch_bounds__(512) void coarse_scatter_kernel(const int* __restrict__ src,
                                                             const int* __restrict__ dst,
                                                             const int* __restrict__ dist,
                                                             int* __restrict__ gcur,
                                                             int* __restrict__ coarse) {
    __shared__ int cnt[512];
    __shared__ int scn[512];
    __shared__ int lofs[512];
    __shared__ int gb[512];
    __shared__ int staging[CH];
    __shared__ int tgt[CH];
    int t = threadIdx.x;
    int base = blockIdx.x * CH;

    cnt[t] = 0;
    __syncthreads();

    int val[16], bb[16];
#pragma unroll
    for (int jj = 0; jj < 16; ++jj) {
        int e = base + jj * 512 + t;
        if (e < EE) {
            int d = dst[e];
            int b = d >> 8;
            bb[jj] = b;
            val[jj] = src[e] | (dist[e] << 17) | ((d & 255) << 20);
            atomicAdd(&cnt[b], 1);
        } else {
            bb[jj] = -1;
            val[jj] = 0;
        }
    }
    __syncthreads();

    int c = cnt[t];
    scn[t] = c;
    __syncthreads();
    for (int off = 1; off < 512; off <<= 1) {
        int x = (t >= off) ? scn[t - off] : 0;
        __syncthreads();
        scn[t] += x;
        __syncthreads();
    }
    lofs[t] = scn[t] - c;
    if (t < NBUK && c > 0) gb[t] = atomicAdd(&gcur[t], c);
    cnt[t] = 0;  // reuse as second counter
    __syncthreads();

#pragma unroll
    for (int jj = 0; jj < 16; ++jj) {
        int b = bb[jj];
        if (b >= 0) {
            int pos = atomicAdd(&cnt[b], 1);
            int slot = lofs[b] + pos;
            staging[slot] = val[jj];
            tgt[slot] = gb[b] + pos;
        }
    }
    __syncthreads();

    int total = scn[511];
    for (int j = t; j < total; j += 512) coarse[tgt[j]] = staging[j];
}

// Fine scatter v2: one block per bucket. Pass A: LDS histogram of the 256
// in-bucket node slots + LDS scan -> per-node CSR offsets (written to global).
// Pass B: scatter via LDS cursors. No global per-node atomics anywhere.
__global__ __launch_bounds__(512) void fine_scatter_kernel(const int* __restrict__ coarse,
                                                           const int* __restrict__ bbase,
                                                           int* __restrict__ offsets,
                                                           int* __restrict__ sorted) {
    __shared__ int cnt[256];
    __shared__ int scn[256];
    __shared__ int cur[256];
    int b = blockIdx.x;
    int t = threadIdx.x;
    if (t < 256) cnt[t] = 0;
    __syncthreads();
    int sb = bbase[b], se = bbase[b + 1];
    for (int idx = sb + t; idx < se; idx += 512)
        atomicAdd(&cnt[(coarse[idx] >> 20) & 255], 1);
    __syncthreads();
    int c = (t < 256) ? cnt[t] : 0;
    if (t < 256) scn[t] = c;
    __syncthreads();
    for (int off = 1; off < 256; off <<= 1) {
        int x = 0;
        if (t < 256 && t >= off) x = scn[t - off];
        __syncthreads();
        if (t < 256) scn[t] += x;
        __syncthreads();
    }
    if (t < 256) {
        int pos = sb + scn[t] - c;  // exclusive prefix within bucket
        int node = (b << 8) + t;
        if (node < NN) offsets[node] = pos;
        cur[t] = pos;
    }
    __syncthreads();
    for (int idx = sb + t; idx < se; idx += 512) {
        int v = coarse[idx];
        int p = atomicAdd(&cur[(v >> 20) & 255], 1);
        sorted[p] = (v & 0x1FFFF) | (((v >> 17) & 7) << 20);  // src | dist<<20
    }
}

// ---------------------------------------------------------------- converts

// transpose + bf16-convert all 7 weights: dst[wi][n][k] = W[wi][k][n]
__global__ __launch_bounds__(256) void prep_w_kernel(const float* W0, const float* W1,
                                                     const float* W2, const float* W3,
                                                     const float* W4, const float* W5,
                                                     const float* W6,
                                                     unsigned short* __restrict__ dst) {
    int idx = blockIdx.x * 256 + threadIdx.x;
    if (idx >= 7 * 16384) return;
    int wi = idx / 16384, r = idx - wi * 16384;
    int n = r & 127, k = r >> 7;
    const float* W = wi == 0 ? W0 : wi == 1 ? W1 : wi == 2 ? W2 : wi == 3 ? W3
                   : wi == 4 ? W4 : wi == 5 ? W5 : W6;
    int ncol = (wi == 6) ? CC : 128;
    float v = (n < ncol) ? W[k * ncol + n] : 0.f;
    dst[wi * 16384 + n * 128 + k] = f2b(v);
}

// ------------------------------------------------------------------- GEMM
// U = (TRANSFORM ? relu(a*Z+d) : Z) @ W + bias  on bf16 inputs, fp32 MFMA accum.
// CVTIN: Zin is fp32 (the raw x input), converted to bf16 during LDS staging.

template <int NT, bool TRANSFORM, bool STATS, bool OUTF32, bool CVTIN>
__global__ __launch_bounds__(256) void mfma_gemm(const void* __restrict__ ZinV,
                                                 const unsigned short* __restrict__ Wt,
                                                 const float* __restrict__ bias, int ncol_real,
                                                 const float* __restrict__ ab,
                                                 void* __restrict__ Uout,
                                                 float* __restrict__ stats) {
    __shared__ unsigned short Zs[128 * 128];
    __shared__ unsigned short Ws[NT * 16 * 128];
    int t = threadIdx.x;
    int m0 = blockIdx.x * 128;
    int c8 = t & 15;  // 16B chunk (8 bf16) within a 128-elem row

    float av[8], dv[8];
    if constexpr (TRANSFORM) {
#pragma unroll
        for (int j = 0; j < 8; ++j) {
            av[j] = ab[c8 * 8 + j];
            dv[j] = ab[128 + c8 * 8 + j];
        }
    }
    // stage A
#pragma unroll
    for (int it = 0; it < 8; ++it) {
        int chunk = it * 256 + t;
        int r = chunk >> 4;
        int gr = m0 + r;
        bf16x8 v = {};
        if constexpr (CVTIN) {
            const float* Zf = (const float*)ZinV;
            if (gr < NN) {
                float4 f0 = *(const float4*)(Zf + (size_t)gr * 128 + c8 * 8);
                float4 f1 = *(const float4*)(Zf + (size_t)gr * 128 + c8 * 8 + 4);
                v[0] = (short)f2b(f0.x); v[1] = (short)f2b(f0.y);
                v[2] = (short)f2b(f0.z); v[3] = (short)f2b(f0.w);
                v[4] = (short)f2b(f1.x); v[5] = (short)f2b(f1.y);
                v[6] = (short)f2b(f1.z); v[7] = (short)f2b(f1.w);
            }
        } else {
            const unsigned short* Zin = (const unsigned short*)ZinV;
            if (gr < NN) v = *(const bf16x8*)(Zin + (size_t)gr * 128 + c8 * 8);
            if constexpr (TRANSFORM) {
#pragma unroll
                for (int j = 0; j < 8; ++j) {
                    float f = fmaxf(0.f, fmaf(av[j], b2f((unsigned short)v[j]), dv[j]));
                    v[j] = (short)f2b(f);
                }
            }
        }
        int ks = c8 * 8;
        *(bf16x8*)(&Zs[r * 128 + (ks ^ ((r & 7) << 3))]) = v;
    }
    // stage W^T
    for (int chunk = t; chunk < NT * 16 * 16; chunk += 256) {
        int r = chunk >> 4, cc = chunk & 15;
        bf16x8 v = *(const bf16x8*)(Wt + r * 128 + cc * 8);
        int ks = cc * 8;
        *(bf16x8*)(&Ws[r * 128 + (ks ^ ((r & 7) << 3))]) = v;
    }
    __syncthreads();

    int l = t & 63, w = t >> 6;
    int lr = l & 15, lg = l >> 4;

    f32x4 acc[2][NT];
#pragma unroll
    for (int mt = 0; mt < 2; ++mt)
#pragma unroll
        for (int nt = 0; nt < NT; ++nt) acc[mt][nt] = (f32x4){0.f, 0.f, 0.f, 0.f};

#pragma unroll
    for (int kc = 0; kc < 4; ++kc) {
        int ks = kc * 32 + lg * 8;
        bf16x8 afr[2];
#pragma unroll
        for (int mt = 0; mt < 2; ++mt) {
            int row = w * 32 + mt * 16 + lr;
            afr[mt] = *(const bf16x8*)(&Zs[row * 128 + (ks ^ ((row & 7) << 3))]);
        }
#pragma unroll
        for (int nt = 0; nt < NT; ++nt) {
            int n = nt * 16 + lr;
            bf16x8 bfr = *(const bf16x8*)(&Ws[n * 128 + (ks ^ ((n & 7) << 3))]);
            acc[0][nt] = __builtin_amdgcn_mfma_f32_16x16x32_bf16(afr[0], bfr, acc[0][nt], 0, 0, 0);
            acc[1][nt] = __builtin_amdgcn_mfma_f32_16x16x32_bf16(afr[1], bfr, acc[1][nt], 0, 0, 0);
        }
    }

    float bv[NT];
#pragma unroll
    for (int nt = 0; nt < NT; ++nt) {
        int col = nt * 16 + lr;
        bv[nt] = (col < ncol_real) ? bias[col] : 0.f;
    }
    float s1[NT], s2[NT];
    if constexpr (STATS) {
#pragma unroll
        for (int nt = 0; nt < NT; ++nt) { s1[nt] = 0.f; s2[nt] = 0.f; }
    }

#pragma unroll
    for (int mt = 0; mt < 2; ++mt) {
#pragma unroll
        for (int j = 0; j < 4; ++j) {
            int row = m0 + w * 32 + mt * 16 + lg * 4 + j;
            bool rv = row < NN;
#pragma unroll
            for (int nt = 0; nt < NT; ++nt) {
                float val = acc[mt][nt][j] + bv[nt];
                int col = nt * 16 + lr;
                if constexpr (STATS) {
                    if (rv) { s1[nt] += val; s2[nt] += val * val; }
                }
                if (rv && col < ncol_real) {
                    if constexpr (OUTF32)
                        ((float*)Uout)[(size_t)row * ncol_real + col] = val;
                    else
                        ((unsigned short*)Uout)[(size_t)row * 128 + col] = f2b(val);
                }
            }
        }
    }

    if constexpr (STATS) {
        float* slot = stats + (blockIdx.x & 31) * 256;
#pragma unroll
        for (int nt = 0; nt < NT; ++nt) {
            float a = s1[nt], b = s2[nt];
            a += __shfl_xor(a, 16, 64);
            b += __shfl_xor(b, 16, 64);
            a += __shfl_xor(a, 32, 64);
            b += __shfl_xor(b, 32, 64);
            if (lg == 0) {
                atomicAdd(slot + nt * 16 + lr, a);
                atomicAdd(slot + 128 + nt * 16 + lr, b);
            }
        }
    }
}

// ---------------------------------------------------------------- finalize
// a = g*rsqrt(var+eps); d = beta - a*mean   =>  h = relu(a*u + d)
__global__ void bn_finalize_kernel(const float* __restrict__ stats, const float* __restrict__ g,
                                   const float* __restrict__ beta, float* __restrict__ ab) {
    int ci = threadIdx.x;
    float s = 0.f, s2 = 0.f;
    for (int k = 0; k < 32; ++k) {
        s += stats[k * 256 + ci];
        s2 += stats[k * 256 + 128 + ci];
    }
    float m = s * (1.0f / NN);
    float var = s2 * (1.0f / NN) - m * m;
    float a = g[ci] * rsqrtf(var + 1e-5f);
    ab[ci] = a;
    ab[128 + ci] = beta[ci] - a * m;
}

// -------------------------------------------------------------- aggregation
// Z[i] = h(i) + sum_{e: dst=i} w[dist_e] * h(src_e),  h(j) = relu(a*U[j]+d)
// 128 thr = 8 edge-slots (16 lanes each); lane owns 8 cols via one uint4 load.
// Each slot batches 4 gathers (32 outstanding/block) -> half the load-issue
// count of the uint2 version at the same memory-level parallelism.
__global__ __launch_bounds__(128) void agg_kernel(const unsigned short* __restrict__ U,
                                                  const int* __restrict__ offsets,
                                                  const int* __restrict__ sorted,
                                                  const float* __restrict__ ab,
                                                  const float* __restrict__ wsm,
                                                  unsigned short* __restrict__ Z) {
    __shared__ int ebuf[128];
    __shared__ float wl[8];
    __shared__ float red[8][128];
    int i = blockIdx.x;
    int t = threadIdx.x;
    int slot = t >> 4;  // 0..7
    int sl = t & 15;    // cols sl*8 .. sl*8+7
    if (t < KK) wl[t] = wsm[t];

    float av[8], dv[8];
#pragma unroll
    for (int j = 0; j < 8; ++j) {
        av[j] = ab[sl * 8 + j];
        dv[j] = ab[128 + sl * 8 + j];
    }

    int beg = offsets[i], end = offsets[i + 1];
    float acc[8] = {};

    for (int base = beg; base < end; base += 128) {
        int n = end - base;
        if (n > 128) n = 128;
        __syncthreads();  // ebuf reuse + wl visibility
        if (t < n) ebuf[t] = sorted[base + t];
        __syncthreads();
        int nfull = n & ~31;
        // bulk: slot takes edges [j0+4*slot .. +3] of each 32-stripe
        for (int j0 = slot * 4; j0 < nfull; j0 += 32) {
            uint4 uu[4];
            float ww[4];
#pragma unroll
            for (int k = 0; k < 4; ++k) {
                int e = ebuf[j0 + k];
                ww[k] = wl[e >> 20];
                uu[k] = *(const uint4*)((const char*)U +
                                        ((unsigned int)(e & 0xFFFFF) << 8) + (sl << 4));
            }
#pragma unroll
            for (int k = 0; k < 4; ++k) {
                acc[0] = fmaf(ww[k], fmaxf(0.f, fmaf(av[0], b2f_lo(uu[k].x), dv[0])), acc[0]);
                acc[1] = fmaf(ww[k], fmaxf(0.f, fmaf(av[1], b2f_hi(uu[k].x), dv[1])), acc[1]);
                acc[2] = fmaf(ww[k], fmaxf(0.f, fmaf(av[2], b2f_lo(uu[k].y), dv[2])), acc[2]);
                acc[3] = fmaf(ww[k], fmaxf(0.f, fmaf(av[3], b2f_hi(uu[k].y), dv[3])), acc[3]);
                acc[4] = fmaf(ww[k], fmaxf(0.f, fmaf(av[4], b2f_lo(uu[k].z), dv[4])), acc[4]);
                acc[5] = fmaf(ww[k], fmaxf(0.f, fmaf(av[5], b2f_hi(uu[k].z), dv[5])), acc[5]);
                acc[6] = fmaf(ww[k], fmaxf(0.f, fmaf(av[6], b2f_lo(uu[k].w), dv[6])), acc[6]);
                acc[7] = fmaf(ww[k], fmaxf(0.f, fmaf(av[7], b2f_hi(uu[k].w), dv[7])), acc[7]);
            }
        }
        // tail: one edge per slot per pass
        for (int j = nfull + slot; j < n; j += 8) {
            int e = ebuf[j];
            float w = wl[e >> 20];
            uint4 u = *(const uint4*)((const char*)U +
                                      ((unsigned int)(e & 0xFFFFF) << 8) + (sl << 4));
            acc[0] = fmaf(w, fmaxf(0.f, fmaf(av[0], b2f_lo(u.x), dv[0])), acc[0]);
            acc[1] = fmaf(w, fmaxf(0.f, fmaf(av[1], b2f_hi(u.x), dv[1])), acc[1]);
            acc[2] = fmaf(w, fmaxf(0.f, fmaf(av[2], b2f_lo(u.y), dv[2])), acc[2]);
            acc[3] = fmaf(w, fmaxf(0.f, fmaf(av[3], b2f_hi(u.y), dv[3])), acc[3]);
            acc[4] = fmaf(w, fmaxf(0.f, fmaf(av[4], b2f_lo(u.z), dv[4])), acc[4]);
            acc[5] = fmaf(w, fmaxf(0.f, fmaf(av[5], b2f_hi(u.z), dv[5])), acc[5]);
            acc[6] = fmaf(w, fmaxf(0.f, fmaf(av[6], b2f_lo(u.w), dv[6])), acc[6]);
            acc[7] = fmaf(w, fmaxf(0.f, fmaf(av[7], b2f_hi(u.w), dv[7])), acc[7]);
        }
    }
    *(f32x4*)(&red[slot][sl * 8]) = (f32x4){acc[0], acc[1], acc[2], acc[3]};
    *(f32x4*)(&red[slot][sl * 8 + 4]) = (f32x4){acc[4], acc[5], acc[6], acc[7]};
    __syncthreads();

    // final: thread t owns column t; sum 8 slots + self term; pack pairs
    float s = 0.f;
#pragma unroll
    for (int s8 = 0; s8 < 8; ++s8) s += red[s8][t];
    float u = b2f(U[((size_t)i << 7) + t]);
    s += fmaxf(0.f, fmaf(ab[t], u, ab[128 + t]));
    float so = __shfl_xor(s, 1, 64);
    if ((t & 1) == 0) {
        unsigned int o = (unsigned int)f2b(s) | ((unsigned int)f2b(so) << 16);
        *(unsigned int*)((char*)Z + ((unsigned int)i << 8) + (t << 1)) = o;
    }
}

// ------------------------------------------------------------------ launch

extern "C" void kernel_launch(void* const* d_in, const int* in_sizes, int n_in,
                              void* d_out, int out_size, void* d_ws, size_t ws_size,
                              hipStream_t stream) {
    const float* x = (const float*)d_in[0];
    const int* ei = (const int*)d_in[1];
    const int* ed = (const int*)d_in[2];
    const float* Wi = (const float*)d_in[3];
    const float* bi = (const float*)d_in[4];
    const float* gi = (const float*)d_in[5];
    const float* bti = (const float*)d_in[6];
    const float* hc0 = (const float*)d_in[7];
    const float* W0a = (const float*)d_in[8];
    const float* b0a = (const float*)d_in[9];
    const float* g0a = (const float*)d_in[10];
    const float* bt0a = (const float*)d_in[11];
    const float* W0b = (const float*)d_in[12];
    const float* b0b = (const float*)d_in[13];
    const float* g0b = (const float*)d_in[14];
    const float* bt0b = (const float*)d_in[15];
    const float* hc1 = (const float*)d_in[16];
    const float* W1a = (const float*)d_in[17];
    const float* b1a = (const float*)d_in[18];
    const float* g1a = (const float*)d_in[19];
    const float* bt1a = (const float*)d_in[20];
    const float* W1b = (const float*)d_in[21];
    const float* b1b = (const float*)d_in[22];
    const float* g1b = (const float*)d_in[23];
    const float* bt1b = (const float*)d_in[24];
    const float* Wp1 = (const float*)d_in[25];
    const float* bp1 = (const float*)d_in[26];
    const float* gp1 = (const float*)d_in[27];
    const float* btp1 = (const float*)d_in[28];
    const float* Wp2 = (const float*)d_in[29];
    const float* bp2 = (const float*)d_in[30];
    float* out = (float*)d_out;

    const int* srcv = ei;
    const int* dstv = ei + EE;

    // workspace layout (all 16B-aligned)
    unsigned short* bufA = (unsigned short*)d_ws;            // N*128 bf16
    unsigned short* bufB = bufA + (size_t)NN * HH;           // N*128 bf16
    unsigned short* wt = bufB + (size_t)NN * HH;             // 7 * 128*128 bf16 (W^T)
    int* sorted = (int*)(wt + 7 * 16384);                    // E int
    int* coarse = sorted + EE;                               // E int (bucketed)
    int* offsets = coarse + EE;                              // N+1 (padded)
    float* stats = (float*)(offsets + NN + 4);               // 6 stages * 32 slots * 256
    float* bnab = stats + 6 * 32 * 256;                      // 6 stages * (a[128], d[128])
    float* wsm = bnab + 6 * 256;                             // 2 softmax sets (stride 8)
    int* gcur = (int*)(wsm + 16);                            // NBUK coarse cursors (512)
    int* bdeg = gcur + 512;                                  // NBUK bucket degrees (512)
    int* bbase = bdeg + 512;                                 // NBUK+1 bucket bases

    // one memset covers stats..bdeg (bnab/wsm/gcur rewritten before use)
    hipMemsetAsync(stats, 0, (size_t)(6 * 32 * 256 + 6 * 256 + 16 + 512 + 512) * 4, stream);

    // CSR build (reused by both layers)
    bucket_hist_kernel<<<(EE + CH2 - 1) / CH2, 512, 0, stream>>>(dstv, bdeg);
    bucket_scan_kernel<<<1, 512, 0, stream>>>(bdeg, bbase, gcur, offsets, hc0, hc1, wsm);
    coarse_scatter_kernel<<<(EE + CH - 1) / CH, 512, 0, stream>>>(srcv, dstv, ed, gcur, coarse);
    fine_scatter_kernel<<<NBUK, 512, 0, stream>>>(coarse, bbase, offsets, sorted);

    prep_w_kernel<<<(7 * 16384 + 255) / 256, 256, 0, stream>>>(Wi, W0a, W0b, W1a, W1b, Wp1, Wp2, wt);

    int gg = (NN + 127) / 128;

    // initial MLP (fp32 x converted in-kernel)
    mfma_gemm<8, false, true, false, true><<<gg, 256, 0, stream>>>(x, wt, bi, 128, nullptr, bufA,
                                                                   stats);
    bn_finalize_kernel<<<1, 128, 0, stream>>>(stats, gi, bti, bnab);

    // SPN layer 0
    agg_kernel<<<NN, 128, 0, stream>>>(bufA, offsets, sorted, bnab, wsm, bufB);
    mfma_gemm<8, false, true, false, false><<<gg, 256, 0, stream>>>(bufB, wt + 16384, b0a, 128,
                                                                    nullptr, bufA, stats + 8192);
    bn_finalize_kernel<<<1, 128, 0, stream>>>(stats + 8192, g0a, bt0a, bnab + 256);
    mfma_gemm<8, true, true, false, false><<<gg, 256, 0, stream>>>(bufA, wt + 2 * 16384, b0b, 128,
                                                                   bnab + 256, bufB,
                                                                   stats + 2 * 8192);
    bn_finalize_kernel<<<1, 128, 0, stream>>>(stats + 2 * 8192, g0b, bt0b, bnab + 512);

    // SPN layer 1
    agg_kernel<<<NN, 128, 0, stream>>>(bufB, offsets, sorted, bnab + 512, wsm + 8, bufA);
    mfma_gemm<8, false, true, false, false><<<gg, 256, 0, stream>>>(bufA, wt + 3 * 16384, b1a, 128,
                                                                    nullptr, bufB, stats + 3 * 8192);
    bn_finalize_kernel<<<1, 128, 0, stream>>>(stats + 3 * 8192, g1a, bt1a, bnab + 768);
    mfma_gemm<8, true, true, false, false><<<gg, 256, 0, stream>>>(bufB, wt + 4 * 16384, b1b, 128,
                                                                   bnab + 768, bufA,
                                                                   stats + 4 * 8192);
    bn_finalize_kernel<<<1, 128, 0, stream>>>(stats + 4 * 8192, g1b, bt1b, bnab + 1024);

    // head
    mfma_gemm<8, true, true, false, false><<<gg, 256, 0, stream>>>(bufA, wt + 5 * 16384, bp1, 128,
                                                                   bnab + 1024, bufB,
                                                                   stats + 5 * 8192);
    bn_finalize_kernel<<<1, 128, 0, stream>>>(stats + 5 * 8192, gp1, btp1, bnab + 1280);
    mfma_gemm<3, true, false, true, false><<<gg, 256, 0, stream>>>(bufB, wt + 6 * 16384, bp2, CC,
                                                                   bnab + 1280, out, nullptr);

    (void)in_sizes; (void)n_in; (void)out_size; (void)ws_size;
}

// Round 14
// 557.718 us; speedup vs baseline: 1.3813x; 1.0001x over previous
//
#include <hip/hip_runtime.h>

#define NN 100000
#define EE 3200000
#define HH 128
#define CC 40
#define KK 5
#define NBUK 391   // ceil(NN/256) buckets of 256 nodes
#define CH 8192    // edges per coarse-scatter block
#define CH2 16384  // edges per bucket-hist block

typedef __attribute__((ext_vector_type(8))) short bf16x8;
typedef __attribute__((ext_vector_type(4))) float f32x4;

__device__ inline float b2f(unsigned short u) {
    union { unsigned int i; float f; } c;
    c.i = ((unsigned int)u) << 16;
    return c.f;
}
__device__ inline float b2f_lo(unsigned int u) {
    union { unsigned int i; float f; } c;
    c.i = u << 16;
    return c.f;
}
__device__ inline float b2f_hi(unsigned int u) {
    union { unsigned int i; float f; } c;
    c.i = u & 0xFFFF0000u;
    return c.f;
}
__device__ inline unsigned short f2b(float f) {
    union { float f; unsigned int i; } c;
    c.f = f;
    unsigned int r = c.i + 0x7FFFu + ((c.i >> 16) & 1u);
    return (unsigned short)(r >> 16);
}

// ---------------------------------------------------------------- CSR build
// Per-bucket degrees via LDS-aggregated histogram (391 buckets of 256 nodes).
__global__ __launch_bounds__(512) void bucket_hist_kernel(const int* __restrict__ dst,
                                                          int* __restrict__ bdeg) {
    __shared__ int h[512];
    int t = threadIdx.x;
    h[t] = 0;
    __syncthreads();
    int base = blockIdx.x * CH2;
    int end = base + CH2;
    if (end > EE) end = EE;
    for (int e = base + t; e < end; e += 512) atomicAdd(&h[dst[e] >> 8], 1);
    __syncthreads();
    int v = h[t];
    if (v > 0) atomicAdd(&bdeg[t], v);
}

// Single block: scan bucket degrees -> bucket bases + coarse cursors;
// also offsets[NN]=EE and the two hop-weight softmaxes.
__global__ void bucket_scan_kernel(const int* __restrict__ bdeg, int* __restrict__ bbase,
                                   int* __restrict__ gcur, int* __restrict__ offsets,
                                   const float* __restrict__ hc0, const float* __restrict__ hc1,
                                   float* __restrict__ wsm) {
    __shared__ int sh[512];
    int t = threadIdx.x;
    int v = (t < NBUK) ? bdeg[t] : 0;
    sh[t] = v;
    __syncthreads();
    for (int off = 1; off < 512; off <<= 1) {
        int x = (t >= off) ? sh[t - off] : 0;
        __syncthreads();
        sh[t] += x;
        __syncthreads();
    }
    if (t < NBUK) {
        int b = sh[t] - v;  // exclusive prefix
        bbase[t] = b;
        gcur[t] = b;
    }
    if (t == 0) {
        bbase[NBUK] = EE;
        offsets[NN] = EE;
        for (int which = 0; which < 2; ++which) {
            const float* hc = which ? hc1 : hc0;
            float mx = hc[0];
            for (int k = 1; k < KK; ++k) mx = fmaxf(mx, hc[k]);
            float ex0 = expf(hc[0] - mx), ex1 = expf(hc[1] - mx), ex2 = expf(hc[2] - mx);
            float ex3 = expf(hc[3] - mx), ex4 = expf(hc[4] - mx);
            float inv = 1.0f / (ex0 + ex1 + ex2 + ex3 + ex4);
            wsm[which * 8 + 0] = ex0 * inv;
            wsm[which * 8 + 1] = ex1 * inv;
            wsm[which * 8 + 2] = ex2 * inv;
            wsm[which * 8 + 3] = ex3 * inv;
            wsm[which * 8 + 4] = ex4 * inv;
        }
    }
}

// Coarse scatter: bin edges into NBUK buckets (dst>>8) with LDS staging so
// global writes are consecutive runs (line-merged) instead of random 4B.
// Payload: src(17b) | dist<<17 (3b) | (dst&255)<<20 (8b).
__global__ __launch_bounds__(512) void coarse_scatter_kernel(const int* __restrict__ src,
                                                             const int* __restrict__ dst,
                                                             const int* __restrict__ dist,
                                                             int* __restrict__ gcur,
                                                             int* __restrict__ coarse) {
    __shared__ int cnt[512];
    __shared__ int scn[512];
    __shared__ int lofs[512];
    __shared__ int gb[512];
    __shared__ int staging[CH];
    __shared__ int tgt[CH];
    int t = threadIdx.x;
    int base = blockIdx.x * CH;

    cnt[t] = 0;
    __syncthreads();

    int val[16], bb[16];
#pragma unroll
    for (int jj = 0; jj < 16; ++jj) {
        int e = base + jj * 512 + t;
        if (e < EE) {
            int d = dst[e];
            int b = d >> 8;
            bb[jj] = b;
            val[jj] = src[e] | (dist[e] << 17) | ((d & 255) << 20);
            atomicAdd(&cnt[b], 1);
        } else {
            bb[jj] = -1;
            val[jj] = 0;
        }
    }
    __syncthreads();

    int c = cnt[t];
    scn[t] = c;
    __syncthreads();
    for (int off = 1; off < 512; off <<= 1) {
        int x = (t >= off) ? scn[t - off] : 0;
        __syncthreads();
        scn[t] += x;
        __syncthreads();
    }
    lofs[t] = scn[t] - c;
    if (t < NBUK && c > 0) gb[t] = atomicAdd(&gcur[t], c);
    cnt[t] = 0;  // reuse as second counter
    __syncthreads();

#pragma unroll
    for (int jj = 0; jj < 16; ++jj) {
        int b = bb[jj];
        if (b >= 0) {
            int pos = atomicAdd(&cnt[b], 1);
            int slot = lofs[b] + pos;
            staging[slot] = val[jj];
            tgt[slot] = gb[b] + pos;
        }
    }
    __syncthreads();

    int total = scn[511];
    for (int j = t; j < total; j += 512) coarse[tgt[j]] = staging[j];
}

// Fine scatter v2: one block per bucket. Pass A: LDS histogram of the 256
// in-bucket node slots + LDS scan -> per-node CSR offsets (written to global).
// Pass B: scatter via LDS cursors. No global per-node atomics anywhere.
__global__ __launch_bounds__(512) void fine_scatter_kernel(const int* __restrict__ coarse,
                                                           const int* __restrict__ bbase,
                                                           int* __restrict__ offsets,
                                                           int* __restrict__ sorted) {
    __shared__ int cnt[256];
    __shared__ int scn[256];
    __shared__ int cur[256];
    int b = blockIdx.x;
    int t = threadIdx.x;
    if (t < 256) cnt[t] = 0;
    __syncthreads();
    int sb = bbase[b], se = bbase[b + 1];
    for (int idx = sb + t; idx < se; idx += 512)
        atomicAdd(&cnt[(coarse[idx] >> 20) & 255], 1);
    __syncthreads();
    int c = (t < 256) ? cnt[t] : 0;
    if (t < 256) scn[t] = c;
    __syncthreads();
    for (int off = 1; off < 256; off <<= 1) {
        int x = 0;
        if (t < 256 && t >= off) x = scn[t - off];
        __syncthreads();
        if (t < 256) scn[t] += x;
        __syncthreads();
    }
    if (t < 256) {
        int pos = sb + scn[t] - c;  // exclusive prefix within bucket
        int node = (b << 8) + t;
        if (node < NN) offsets[node] = pos;
        cur[t] = pos;
    }
    __syncthreads();
    for (int idx = sb + t; idx < se; idx += 512) {
        int v = coarse[idx];
        int p = atomicAdd(&cur[(v >> 20) & 255], 1);
        sorted[p] = (v & 0x1FFFF) | (((v >> 17) & 7) << 20);  // src | dist<<20
    }
}

// ---------------------------------------------------------------- converts

// transpose + bf16-convert all 7 weights: dst[wi][n][k] = W[wi][k][n]
__global__ __launch_bounds__(256) void prep_w_kernel(const float* W0, const float* W1,
                                                     const float* W2, const float* W3,
                                                     const float* W4, const float* W5,
                                                     const float* W6,
                                                     unsigned short* __restrict__ dst) {
    int idx = blockIdx.x * 256 + threadIdx.x;
    if (idx >= 7 * 16384) return;
    int wi = idx / 16384, r = idx - wi * 16384;
    int n = r & 127, k = r >> 7;
    const float* W = wi == 0 ? W0 : wi == 1 ? W1 : wi == 2 ? W2 : wi == 3 ? W3
                   : wi == 4 ? W4 : wi == 5 ? W5 : W6;
    int ncol = (wi == 6) ? CC : 128;
    float v = (n < ncol) ? W[k * ncol + n] : 0.f;
    dst[wi * 16384 + n * 128 + k] = f2b(v);
}

// ------------------------------------------------------------------- GEMM
// U = (TRANSFORM ? relu(a*Z+d) : Z) @ W + bias  on bf16 inputs, fp32 MFMA accum.
// CVTIN: Zin is fp32 (the raw x input), converted to bf16 during LDS staging.

template <int NT, bool TRANSFORM, bool STATS, bool OUTF32, bool CVTIN>
__global__ __launch_bounds__(256) void mfma_gemm(const void* __restrict__ ZinV,
                                                 const unsigned short* __restrict__ Wt,
                                                 const float* __restrict__ bias, int ncol_real,
                                                 const float* __restrict__ ab,
                                                 void* __restrict__ Uout,
                                                 float* __restrict__ stats) {
    __shared__ unsigned short Zs[128 * 128];
    __shared__ unsigned short Ws[NT * 16 * 128];
    int t = threadIdx.x;
    int m0 = blockIdx.x * 128;
    int c8 = t & 15;  // 16B chunk (8 bf16) within a 128-elem row

    float av[8], dv[8];
    if constexpr (TRANSFORM) {
#pragma unroll
        for (int j = 0; j < 8; ++j) {
            av[j] = ab[c8 * 8 + j];
            dv[j] = ab[128 + c8 * 8 + j];
        }
    }
    // stage A
#pragma unroll
    for (int it = 0; it < 8; ++it) {
        int chunk = it * 256 + t;
        int r = chunk >> 4;
        int gr = m0 + r;
        bf16x8 v = {};
        if constexpr (CVTIN) {
            const float* Zf = (const float*)ZinV;
            if (gr < NN) {
                float4 f0 = *(const float4*)(Zf + (size_t)gr * 128 + c8 * 8);
                float4 f1 = *(const float4*)(Zf + (size_t)gr * 128 + c8 * 8 + 4);
                v[0] = (short)f2b(f0.x); v[1] = (short)f2b(f0.y);
                v[2] = (short)f2b(f0.z); v[3] = (short)f2b(f0.w);
                v[4] = (short)f2b(f1.x); v[5] = (short)f2b(f1.y);
                v[6] = (short)f2b(f1.z); v[7] = (short)f2b(f1.w);
            }
        } else {
            const unsigned short* Zin = (const unsigned short*)ZinV;
            if (gr < NN) v = *(const bf16x8*)(Zin + (size_t)gr * 128 + c8 * 8);
            if constexpr (TRANSFORM) {
#pragma unroll
                for (int j = 0; j < 8; ++j) {
                    float f = fmaxf(0.f, fmaf(av[j], b2f((unsigned short)v[j]), dv[j]));
                    v[j] = (short)f2b(f);
                }
            }
        }
        int ks = c8 * 8;
        *(bf16x8*)(&Zs[r * 128 + (ks ^ ((r & 7) << 3))]) = v;
    }
    // stage W^T
    for (int chunk = t; chunk < NT * 16 * 16; chunk += 256) {
        int r = chunk >> 4, cc = chunk & 15;
        bf16x8 v = *(const bf16x8*)(Wt + r * 128 + cc * 8);
        int ks = cc * 8;
        *(bf16x8*)(&Ws[r * 128 + (ks ^ ((r & 7) << 3))]) = v;
    }
    __syncthreads();

    int l = t & 63, w = t >> 6;
    int lr = l & 15, lg = l >> 4;

    f32x4 acc[2][NT];
#pragma unroll
    for (int mt = 0; mt < 2; ++mt)
#pragma unroll
        for (int nt = 0; nt < NT; ++nt) acc[mt][nt] = (f32x4){0.f, 0.f, 0.f, 0.f};

#pragma unroll
    for (int kc = 0; kc < 4; ++kc) {
        int ks = kc * 32 + lg * 8;
        bf16x8 afr[2];
#pragma unroll
        for (int mt = 0; mt < 2; ++mt) {
            int row = w * 32 + mt * 16 + lr;
            afr[mt] = *(const bf16x8*)(&Zs[row * 128 + (ks ^ ((row & 7) << 3))]);
        }
#pragma unroll
        for (int nt = 0; nt < NT; ++nt) {
            int n = nt * 16 + lr;
            bf16x8 bfr = *(const bf16x8*)(&Ws[n * 128 + (ks ^ ((n & 7) << 3))]);
            acc[0][nt] = __builtin_amdgcn_mfma_f32_16x16x32_bf16(afr[0], bfr, acc[0][nt], 0, 0, 0);
            acc[1][nt] = __builtin_amdgcn_mfma_f32_16x16x32_bf16(afr[1], bfr, acc[1][nt], 0, 0, 0);
        }
    }

    float bv[NT];
#pragma unroll
    for (int nt = 0; nt < NT; ++nt) {
        int col = nt * 16 + lr;
        bv[nt] = (col < ncol_real) ? bias[col] : 0.f;
    }
    float s1[NT], s2[NT];
    if constexpr (STATS) {
#pragma unroll
        for (int nt = 0; nt < NT; ++nt) { s1[nt] = 0.f; s2[nt] = 0.f; }
    }

#pragma unroll
    for (int mt = 0; mt < 2; ++mt) {
#pragma unroll
        for (int j = 0; j < 4; ++j) {
            int row = m0 + w * 32 + mt * 16 + lg * 4 + j;
            bool rv = row < NN;
#pragma unroll
            for (int nt = 0; nt < NT; ++nt) {
                float val = acc[mt][nt][j] + bv[nt];
                int col = nt * 16 + lr;
                if constexpr (STATS) {
                    if (rv) { s1[nt] += val; s2[nt] += val * val; }
                }
                if (rv && col < ncol_real) {
                    if constexpr (OUTF32)
                        ((float*)Uout)[(size_t)row * ncol_real + col] = val;
                    else
                        ((unsigned short*)Uout)[(size_t)row * 128 + col] = f2b(val);
                }
            }
        }
    }

    if constexpr (STATS) {
        float* slot = stats + (blockIdx.x & 31) * 256;
#pragma unroll
        for (int nt = 0; nt < NT; ++nt) {
            float a = s1[nt], b = s2[nt];
            a += __shfl_xor(a, 16, 64);
            b += __shfl_xor(b, 16, 64);
            a += __shfl_xor(a, 32, 64);
            b += __shfl_xor(b, 32, 64);
            if (lg == 0) {
                atomicAdd(slot + nt * 16 + lr, a);
                atomicAdd(slot + 128 + nt * 16 + lr, b);
            }
        }
    }
}

// ---------------------------------------------------------------- finalize
// a = g*rsqrt(var+eps); d = beta - a*mean   =>  h = relu(a*u + d)
__global__ void bn_finalize_kernel(const float* __restrict__ stats, const float* __restrict__ g,
                                   const float* __restrict__ beta, float* __restrict__ ab) {
    int ci = threadIdx.x;
    float s = 0.f, s2 = 0.f;
    for (int k = 0; k < 32; ++k) {
        s += stats[k * 256 + ci];
        s2 += stats[k * 256 + 128 + ci];
    }
    float m = s * (1.0f / NN);
    float var = s2 * (1.0f / NN) - m * m;
    float a = g[ci] * rsqrtf(var + 1e-5f);
    ab[ci] = a;
    ab[128 + ci] = beta[ci] - a * m;
}

// -------------------------------------------------------------- aggregation
// Z[i] = h(i) + sum_{e: dst=i} w[dist_e] * h(src_e),  h(j) = relu(a*U[j]+d)
// 128 thr = 8 edge-slots (16 lanes each); lane owns 8 cols via one uint4 load.
// Each slot batches 4 gathers (32 outstanding/block).
__global__ __launch_bounds__(128) void agg_kernel(const unsigned short* __restrict__ U,
                                                  const int* __restrict__ offsets,
                                                  const int* __restrict__ sorted,
                                                  const float* __restrict__ ab,
                                                  const float* __restrict__ wsm,
                                                  unsigned short* __restrict__ Z) {
    __shared__ int ebuf[128];
    __shared__ float wl[8];
    __shared__ float red[8][128];
    int i = blockIdx.x;
    int t = threadIdx.x;
    int slot = t >> 4;  // 0..7
    int sl = t & 15;    // cols sl*8 .. sl*8+7
    if (t < KK) wl[t] = wsm[t];

    float av[8], dv[8];
#pragma unroll
    for (int j = 0; j < 8; ++j) {
        av[j] = ab[sl * 8 + j];
        dv[j] = ab[128 + sl * 8 + j];
    }

    int beg = offsets[i], end = offsets[i + 1];
    float acc[8] = {};

    for (int base = beg; base < end; base += 128) {
        int n = end - base;
        if (n > 128) n = 128;
        __syncthreads();  // ebuf reuse + wl visibility
        if (t < n) ebuf[t] = sorted[base + t];
        __syncthreads();
        int nfull = n & ~31;
        // bulk: slot takes edges [j0+4*slot .. +3] of each 32-stripe
        for (int j0 = slot * 4; j0 < nfull; j0 += 32) {
            uint4 uu[4];
            float ww[4];
#pragma unroll
            for (int k = 0; k < 4; ++k) {
                int e = ebuf[j0 + k];
                ww[k] = wl[e >> 20];
                uu[k] = *(const uint4*)((const char*)U +
                                        ((unsigned int)(e & 0xFFFFF) << 8) + (sl << 4));
            }
#pragma unroll
            for (int k = 0; k < 4; ++k) {
                acc[0] = fmaf(ww[k], fmaxf(0.f, fmaf(av[0], b2f_lo(uu[k].x), dv[0])), acc[0]);
                acc[1] = fmaf(ww[k], fmaxf(0.f, fmaf(av[1], b2f_hi(uu[k].x), dv[1])), acc[1]);
                acc[2] = fmaf(ww[k], fmaxf(0.f, fmaf(av[2], b2f_lo(uu[k].y), dv[2])), acc[2]);
                acc[3] = fmaf(ww[k], fmaxf(0.f, fmaf(av[3], b2f_hi(uu[k].y), dv[3])), acc[3]);
                acc[4] = fmaf(ww[k], fmaxf(0.f, fmaf(av[4], b2f_lo(uu[k].z), dv[4])), acc[4]);
                acc[5] = fmaf(ww[k], fmaxf(0.f, fmaf(av[5], b2f_hi(uu[k].z), dv[5])), acc[5]);
                acc[6] = fmaf(ww[k], fmaxf(0.f, fmaf(av[6], b2f_lo(uu[k].w), dv[6])), acc[6]);
                acc[7] = fmaf(ww[k], fmaxf(0.f, fmaf(av[7], b2f_hi(uu[k].w), dv[7])), acc[7]);
            }
        }
        // tail: one edge per slot per pass
        for (int j = nfull + slot; j < n; j += 8) {
            int e = ebuf[j];
            float w = wl[e >> 20];
            uint4 u = *(const uint4*)((const char*)U +
                                      ((unsigned int)(e & 0xFFFFF) << 8) + (sl << 4));
            acc[0] = fmaf(w, fmaxf(0.f, fmaf(av[0], b2f_lo(u.x), dv[0])), acc[0]);
            acc[1] = fmaf(w, fmaxf(0.f, fmaf(av[1], b2f_hi(u.x), dv[1])), acc[1]);
            acc[2] = fmaf(w, fmaxf(0.f, fmaf(av[2], b2f_lo(u.y), dv[2])), acc[2]);
            acc[3] = fmaf(w, fmaxf(0.f, fmaf(av[3], b2f_hi(u.y), dv[3])), acc[3]);
            acc[4] = fmaf(w, fmaxf(0.f, fmaf(av[4], b2f_lo(u.z), dv[4])), acc[4]);
            acc[5] = fmaf(w, fmaxf(0.f, fmaf(av[5], b2f_hi(u.z), dv[5])), acc[5]);
            acc[6] = fmaf(w, fmaxf(0.f, fmaf(av[6], b2f_lo(u.w), dv[6])), acc[6]);
            acc[7] = fmaf(w, fmaxf(0.f, fmaf(av[7], b2f_hi(u.w), dv[7])), acc[7]);
        }
    }
    *(f32x4*)(&red[slot][sl * 8]) = (f32x4){acc[0], acc[1], acc[2], acc[3]};
    *(f32x4*)(&red[slot][sl * 8 + 4]) = (f32x4){acc[4], acc[5], acc[6], acc[7]};
    __syncthreads();

    // final: thread t owns column t; sum 8 slots + self term; pack pairs
    float s = 0.f;
#pragma unroll
    for (int s8 = 0; s8 < 8; ++s8) s += red[s8][t];
    float u = b2f(U[((size_t)i << 7) + t]);
    s += fmaxf(0.f, fmaf(ab[t], u, ab[128 + t]));
    float so = __shfl_xor(s, 1, 64);
    if ((t & 1) == 0) {
        unsigned int o = (unsigned int)f2b(s) | ((unsigned int)f2b(so) << 16);
        *(unsigned int*)((char*)Z + ((unsigned int)i << 8) + (t << 1)) = o;
    }
}

// ------------------------------------------------------------------ launch

extern "C" void kernel_launch(void* const* d_in, const int* in_sizes, int n_in,
                              void* d_out, int out_size, void* d_ws, size_t ws_size,
                              hipStream_t stream) {
    const float* x = (const float*)d_in[0];
    const int* ei = (const int*)d_in[1];
    const int* ed = (const int*)d_in[2];
    const float* Wi = (const float*)d_in[3];
    const float* bi = (const float*)d_in[4];
    const float* gi = (const float*)d_in[5];
    const float* bti = (const float*)d_in[6];
    const float* hc0 = (const float*)d_in[7];
    const float* W0a = (const float*)d_in[8];
    const float* b0a = (const float*)d_in[9];
    const float* g0a = (const float*)d_in[10];
    const float* bt0a = (const float*)d_in[11];
    const float* W0b = (const float*)d_in[12];
    const float* b0b = (const float*)d_in[13];
    const float* g0b = (const float*)d_in[14];
    const float* bt0b = (const float*)d_in[15];
    const float* hc1 = (const float*)d_in[16];
    const float* W1a = (const float*)d_in[17];
    const float* b1a = (const float*)d_in[18];
    const float* g1a = (const float*)d_in[19];
    const float* bt1a = (const float*)d_in[20];
    const float* W1b = (const float*)d_in[21];
    const float* b1b = (const float*)d_in[22];
    const float* g1b = (const float*)d_in[23];
    const float* bt1b = (const float*)d_in[24];
    const float* Wp1 = (const float*)d_in[25];
    const float* bp1 = (const float*)d_in[26];
    const float* gp1 = (const float*)d_in[27];
    const float* btp1 = (const float*)d_in[28];
    const float* Wp2 = (const float*)d_in[29];
    const float* bp2 = (const float*)d_in[30];
    float* out = (float*)d_out;

    const int* srcv = ei;
    const int* dstv = ei + EE;

    // workspace layout (all 16B-aligned)
    unsigned short* bufA = (unsigned short*)d_ws;            // N*128 bf16
    unsigned short* bufB = bufA + (size_t)NN * HH;           // N*128 bf16
    unsigned short* wt = bufB + (size_t)NN * HH;             // 7 * 128*128 bf16 (W^T)
    int* sorted = (int*)(wt + 7 * 16384);                    // E int
    int* coarse = sorted + EE;                               // E int (bucketed)
    int* offsets = coarse + EE;                              // N+1 (padded)
    float* stats = (float*)(offsets + NN + 4);               // 6 stages * 32 slots * 256
    float* bnab = stats + 6 * 32 * 256;                      // 6 stages * (a[128], d[128])
    float* wsm = bnab + 6 * 256;                             // 2 softmax sets (stride 8)
    int* gcur = (int*)(wsm + 16);                            // NBUK coarse cursors (512)
    int* bdeg = gcur + 512;                                  // NBUK bucket degrees (512)
    int* bbase = bdeg + 512;                                 // NBUK+1 bucket bases

    // one memset covers stats..bdeg (bnab/wsm/gcur rewritten before use)
    hipMemsetAsync(stats, 0, (size_t)(6 * 32 * 256 + 6 * 256 + 16 + 512 + 512) * 4, stream);

    // CSR build (reused by both layers)
    bucket_hist_kernel<<<(EE + CH2 - 1) / CH2, 512, 0, stream>>>(dstv, bdeg);
    bucket_scan_kernel<<<1, 512, 0, stream>>>(bdeg, bbase, gcur, offsets, hc0, hc1, wsm);
    coarse_scatter_kernel<<<(EE + CH - 1) / CH, 512, 0, stream>>>(srcv, dstv, ed, gcur, coarse);
    fine_scatter_kernel<<<NBUK, 512, 0, stream>>>(coarse, bbase, offsets, sorted);

    prep_w_kernel<<<(7 * 16384 + 255) / 256, 256, 0, stream>>>(Wi, W0a, W0b, W1a, W1b, Wp1, Wp2, wt);

    int gg = (NN + 127) / 128;

    // initial MLP (fp32 x converted in-kernel)
    mfma_gemm<8, false, true, false, true><<<gg, 256, 0, stream>>>(x, wt, bi, 128, nullptr, bufA,
                                                                   stats);
    bn_finalize_kernel<<<1, 128, 0, stream>>>(stats, gi, bti, bnab);

    // SPN layer 0
    agg_kernel<<<NN, 128, 0, stream>>>(bufA, offsets, sorted, bnab, wsm, bufB);
    mfma_gemm<8, false, true, false, false><<<gg, 256, 0, stream>>>(bufB, wt + 16384, b0a, 128,
                                                                    nullptr, bufA, stats + 8192);
    bn_finalize_kernel<<<1, 128, 0, stream>>>(stats + 8192, g0a, bt0a, bnab + 256);
    mfma_gemm<8, true, true, false, false><<<gg, 256, 0, stream>>>(bufA, wt + 2 * 16384, b0b, 128,
                                                                   bnab + 256, bufB,
                                                                   stats + 2 * 8192);
    bn_finalize_kernel<<<1, 128, 0, stream>>>(stats + 2 * 8192, g0b, bt0b, bnab + 512);

    // SPN layer 1
    agg_kernel<<<NN, 128, 0, stream>>>(bufB, offsets, sorted, bnab + 512, wsm + 8, bufA);
    mfma_gemm<8, false, true, false, false><<<gg, 256, 0, stream>>>(bufA, wt + 3 * 16384, b1a, 128,
                                                                    nullptr, bufB, stats + 3 * 8192);
    bn_finalize_kernel<<<1, 128, 0, stream>>>(stats + 3 * 8192, g1a, bt1a, bnab + 768);
    mfma_gemm<8, true, true, false, false><<<gg, 256, 0, stream>>>(bufB, wt + 4 * 16384, b1b, 128,
                                                                   bnab + 768, bufA,
                                                                   stats + 4 * 8192);
    bn_finalize_kernel<<<1, 128, 0, stream>>>(stats + 4 * 8192, g1b, bt1b, bnab + 1024);

    // head
    mfma_gemm<8, true, true, false, false><<<gg, 256, 0, stream>>>(bufA, wt + 5 * 16384, bp1, 128,
                                                                   bnab + 1024, bufB,
                                                                   stats + 5 * 8192);
    bn_finalize_kernel<<<1, 128, 0, stream>>>(stats + 5 * 8192, gp1, btp1, bnab + 1280);
    mfma_gemm<3, true, false, true, false><<<gg, 256, 0, stream>>>(bufB, wt + 6 * 16384, bp2, CC,
                                                                   bnab + 1280, out, nullptr);

    (void)in_sizes; (void)n_in; (void)out_size; (void)ws_size;
}